// Round 2
// baseline (5792.004 us; speedup 1.0000x reference)
//
#include <hip/hip_runtime.h>

// ---------------- problem constants ----------------
constexpr int B_SZ = 2, LSEQ = 2048, D_MODEL = 2048;
constexpr int D_SSM = 4096, D_STATE = 128, NHEADS = 64, HEADDIM = 64;
constexpr int CHUNK = 128;
constexpr int NCH = LSEQ / CHUNK;             // 16
constexpr int BL = B_SZ * LSEQ;               // 4096 token rows
constexpr int DIN = 2 * D_SSM + 2 * D_STATE + NHEADS; // 8512
constexpr int DINP = 8576;                    // padded to 67*128
constexpr int CONVDIM = D_SSM + 2 * D_STATE;  // 4352
constexpr int BOFF = D_SSM;                   // B offset inside xBC_conv
constexpr int COFF = D_SSM + D_STATE;         // C offset inside xBC_conv

// ---------------- workspace layout (bytes) — total ~218 MiB ----------------
constexpr size_t OFF_WIN = 0;                                      // W_in bf16 -> later y bf16
constexpr size_t OFF_UB  = OFF_WIN + (size_t)DINP * D_MODEL * 2;   // u bf16 -> later W_out bf16
constexpr size_t OFF_ZX  = OFF_UB + (size_t)BL * D_MODEL * 2;      // zxbcdt bf16 (BL x DINP)
constexpr size_t OFF_XBC = OFF_ZX + (size_t)BL * DINP * 2;         // conv output bf16 (BL x 4352)
constexpr size_t OFF_DT  = OFF_XBC + (size_t)BL * CONVDIM * 2;     // dt fp32 (BL x 64)
constexpr size_t OFF_ST  = OFF_DT + (size_t)BL * NHEADS * 4;       // states fp32 (2048 x 8192), reused as Y
constexpr size_t OFF_CB  = OFF_ST + (size_t)B_SZ * NCH * NHEADS * HEADDIM * D_STATE * 4;
constexpr size_t OFF_DAS = OFF_CB + (size_t)B_SZ * NCH * CHUNK * CHUNK * 4;
constexpr size_t WS_NEED = OFF_DAS + (size_t)B_SZ * NCH * NHEADS * 4 + 4096;

typedef float f32x4 __attribute__((ext_vector_type(4)));
typedef __bf16 bf16x8 __attribute__((ext_vector_type(8)));

__device__ __forceinline__ unsigned short f2bf(float f) {
  unsigned int x = __float_as_uint(f);
  x += 0x7fffu + ((x >> 16) & 1u);   // round-to-nearest-even
  return (unsigned short)(x >> 16);
}
__device__ __forceinline__ float bf2f(unsigned short u) {
  return __uint_as_float(((unsigned int)u) << 16);
}

// ---------------- fp32 -> bf16 convert (with zero padding past nsrc4) ----------------
__global__ void k_cvt4(const float4* __restrict__ src, ushort4* __restrict__ dst,
                       int n4, int nsrc4) {
  int i = blockIdx.x * 256 + threadIdx.x;
  if (i >= n4) return;
  float4 v = make_float4(0.f, 0.f, 0.f, 0.f);
  if (i < nsrc4) v = src[i];
  ushort4 o;
  o.x = f2bf(v.x); o.y = f2bf(v.y); o.z = f2bf(v.z); o.w = f2bf(v.w);
  dst[i] = o;
}

// ---------------- bf16 MFMA GEMM: C[M][N] = A[M][K] * B[N][K]^T ----------------
// 128x128 block tile, 4 waves, each wave 64x64 (4x4 tiles of 16x16x32 MFMA), BK=32.
template <bool OUT_BF16>
__global__ __launch_bounds__(256, 2) void k_gemm_bt(
    const unsigned short* __restrict__ A, const unsigned short* __restrict__ Bm,
    void* __restrict__ Cv, int M, int N, int K) {
  __shared__ __align__(16) unsigned short As[128 * 32];
  __shared__ __align__(16) unsigned short Bs[128 * 32];
  int t = threadIdx.x;
  int m0 = blockIdx.y * 128, n0 = blockIdx.x * 128;
  int w = t >> 6, lane = t & 63;
  int wm = (w >> 1) * 64, wn = (w & 1) * 64;
  int lr = lane & 15, lk = (lane >> 4) * 8;
  f32x4 acc[4][4] = {};
  int sr = t >> 2, sc = (t & 3) * 8;
  const unsigned short* Ap = A + (size_t)(m0 + sr) * K + sc;
  const unsigned short* Bp = Bm + (size_t)(n0 + sr) * K + sc;
  for (int k0 = 0; k0 < K; k0 += 32) {
    int4 a0 = *(const int4*)(Ap + k0);
    int4 a1 = *(const int4*)(Ap + (size_t)64 * K + k0);
    int4 b0 = *(const int4*)(Bp + k0);
    int4 b1 = *(const int4*)(Bp + (size_t)64 * K + k0);
    __syncthreads();
    *(int4*)&As[sr * 32 + sc] = a0;
    *(int4*)&As[(sr + 64) * 32 + sc] = a1;
    *(int4*)&Bs[sr * 32 + sc] = b0;
    *(int4*)&Bs[(sr + 64) * 32 + sc] = b1;
    __syncthreads();
    bf16x8 af[4], bfv[4];
#pragma unroll
    for (int i = 0; i < 4; i++) af[i]  = *(const bf16x8*)&As[(wm + i * 16 + lr) * 32 + lk];
#pragma unroll
    for (int i = 0; i < 4; i++) bfv[i] = *(const bf16x8*)&Bs[(wn + i * 16 + lr) * 32 + lk];
#pragma unroll
    for (int mi = 0; mi < 4; mi++)
#pragma unroll
      for (int ni = 0; ni < 4; ni++)
        acc[mi][ni] = __builtin_amdgcn_mfma_f32_16x16x32_bf16(af[mi], bfv[ni], acc[mi][ni], 0, 0, 0);
  }
  int orow = (lane >> 4) * 4, ocol = lane & 15;
#pragma unroll
  for (int mi = 0; mi < 4; mi++)
#pragma unroll
    for (int ni = 0; ni < 4; ni++) {
      int r0 = m0 + wm + mi * 16 + orow;
      int c0 = n0 + wn + ni * 16 + ocol;
#pragma unroll
      for (int r = 0; r < 4; r++) {
        if (OUT_BF16)
          ((unsigned short*)Cv)[(size_t)(r0 + r) * N + c0] = f2bf(acc[mi][ni][r]);
        else
          ((float*)Cv)[(size_t)(r0 + r) * N + c0] = acc[mi][ni][r];
      }
    }
}

// ---------------- dt = softplus(raw + dt_bias) ----------------
__global__ void k_dt(const unsigned short* __restrict__ zx, const float* __restrict__ dt_bias,
                     float* __restrict__ dt) {
  int id = blockIdx.x * 256 + threadIdx.x;   // BL*64
  int row = id >> 6, h = id & 63;
  float x = bf2f(zx[(size_t)row * DINP + (2 * D_SSM + 2 * D_STATE) + h]) + dt_bias[h];
  dt[id] = (x > 20.f) ? x : log1pf(expf(x));
}

// ---------------- causal depthwise conv (width 3) + bias + SiLU ----------------
__global__ void k_conv(const unsigned short* __restrict__ zx, const float* __restrict__ cw,
                       const float* __restrict__ cbv, unsigned short* __restrict__ out) {
  int id = blockIdx.x * 256 + threadIdx.x;
  if (id >= BL * CONVDIM) return;
  int c = id % CONVDIM;
  int row = id / CONVDIM;
  int b = row >> 11, l = row & 2047;
  float acc = cbv[c];
#pragma unroll
  for (int k = 0; k < 3; k++) {
    int ls = l + k - 2;
    if (ls >= 0)
      acc += bf2f(zx[(size_t)(b * LSEQ + ls) * DINP + D_SSM + c]) * cw[c * 3 + k];
  }
  out[(size_t)row * CONVDIM + c] = f2bf(acc / (1.f + expf(-acc)));
}

// ---------------- CB[l][s] = C[l] . B[s]  per (b,c) chunk (head-independent) ----------------
__global__ __launch_bounds__(256) void k_cb(const unsigned short* __restrict__ xBC,
                                            float* __restrict__ cbuf) {
  int bc = blockIdx.x;          // b*16 + c
  int row0 = bc * CHUNK;
  int t = threadIdx.x;
  __shared__ float Cs[32 * 132];
  int s = t & 127, lh = t >> 7; // lh in {0,1}
  for (int lt = 0; lt < 4; lt++) {
    __syncthreads();
    for (int i = t; i < 32 * 128; i += 256) {
      int l = i >> 7, n = i & 127;
      Cs[l * 132 + n] = bf2f(xBC[(size_t)(row0 + lt * 32 + l) * CONVDIM + COFF + n]);
    }
    __syncthreads();
    float acc[16];
#pragma unroll
    for (int j = 0; j < 16; j++) acc[j] = 0.f;
    const unsigned short* bp = xBC + (size_t)(row0 + s) * CONVDIM + BOFF;
    for (int n4 = 0; n4 < 128; n4 += 4) {
      ushort4 bu = *(const ushort4*)(bp + n4);
      float b0 = bf2f(bu.x), b1 = bf2f(bu.y), b2 = bf2f(bu.z), b3 = bf2f(bu.w);
#pragma unroll
      for (int li = 0; li < 16; li++) {
        float4 cv = *(const float4*)&Cs[(lh * 16 + li) * 132 + n4];
        acc[li] += b0 * cv.x + b1 * cv.y + b2 * cv.z + b3 * cv.w;
      }
    }
#pragma unroll
    for (int li = 0; li < 16; li++) {
      int gl = lt * 32 + lh * 16 + li;
      cbuf[((size_t)bc * 128 + gl) * 128 + s] = acc[li];
    }
  }
}

// ---------------- per-chunk raw states: S[h,p,n] = sum_l B[l,n]*exp(Alast-Acum[l])*x[l,h,p]*dt[l,h]
__global__ __launch_bounds__(256) void k_states(
    const unsigned short* __restrict__ xBC, const float* __restrict__ dt,
    const float* __restrict__ A_log, float* __restrict__ states,
    float* __restrict__ dAsum) {
  int id = blockIdx.x; int h = id & 63; int bc = id >> 6; int row0 = bc * CHUNK;
  int t = threadIdx.x;
  __shared__ float Acum[128];
  __shared__ float wdec[128];
  __shared__ float Bw[32 * 132];
  __shared__ float Xs[32 * 64];
  float Ah = -expf(A_log[h]);
  if (t < 128) Acum[t] = dt[(size_t)(row0 + t) * 64 + h] * Ah;
  __syncthreads();
  for (int off = 1; off < 128; off <<= 1) {
    float v = 0.f;
    bool act = (t < 128) && (t >= off);
    if (act) v = Acum[t - off];
    __syncthreads();
    if (act) Acum[t] += v;
    __syncthreads();
  }
  float Alast = Acum[127];
  if (t < 128) wdec[t] = expf(Alast - Acum[t]);
  if (t == 0) dAsum[id] = Alast;
  float acc[4][8];
#pragma unroll
  for (int a = 0; a < 4; a++)
#pragma unroll
    for (int b = 0; b < 8; b++) acc[a][b] = 0.f;
  int nl = t & 31, p0 = (t >> 5) * 8;
  for (int lc = 0; lc < 4; lc++) {
    __syncthreads();
    for (int i = t; i < 32 * 128; i += 256) {
      int l = i >> 7, n = i & 127;
      Bw[l * 132 + n] = bf2f(xBC[(size_t)(row0 + lc * 32 + l) * CONVDIM + BOFF + n]) * wdec[lc * 32 + l];
    }
    for (int i = t; i < 32 * 64; i += 256) {
      int l = i >> 6, p = i & 63;
      int gr = row0 + lc * 32 + l;
      Xs[l * 64 + p] = bf2f(xBC[(size_t)gr * CONVDIM + h * HEADDIM + p]) * dt[(size_t)gr * 64 + h];
    }
    __syncthreads();
    for (int l = 0; l < 32; l++) {
      float bv[4];
#pragma unroll
      for (int ni = 0; ni < 4; ni++) bv[ni] = Bw[l * 132 + nl + 32 * ni];
      float4 x0 = *(const float4*)&Xs[l * 64 + p0];
      float4 x1 = *(const float4*)&Xs[l * 64 + p0 + 4];
      float xv[8] = {x0.x, x0.y, x0.z, x0.w, x1.x, x1.y, x1.z, x1.w};
#pragma unroll
      for (int ni = 0; ni < 4; ni++)
#pragma unroll
        for (int pi = 0; pi < 8; pi++)
          acc[ni][pi] += bv[ni] * xv[pi];
    }
  }
  float* sp = states + (size_t)id * 8192;
#pragma unroll
  for (int ni = 0; ni < 4; ni++)
#pragma unroll
    for (int pi = 0; pi < 8; pi++)
      sp[(p0 + pi) * 128 + nl + 32 * ni] = acc[ni][pi];
}

// ---------------- inter-chunk recurrence (in-place: raw states -> entering states) ----------------
__global__ __launch_bounds__(256) void k_scan(float* __restrict__ states,
                                              const float* __restrict__ dAsum) {
  int bh = blockIdx.x; int h = bh & 63; int b = bh >> 6;
  int t = threadIdx.x;
  float carry[32];
#pragma unroll
  for (int j = 0; j < 32; j++) carry[j] = 0.f;
  for (int c = 0; c < NCH; c++) {
    int bc = b * NCH + c;
    float* sp = states + ((size_t)bc * 64 + h) * 8192;
    float dec = expf(dAsum[bc * 64 + h]);
    float raw[32];
#pragma unroll
    for (int j = 0; j < 32; j++) raw[j] = sp[t + j * 256];
#pragma unroll
    for (int j = 0; j < 32; j++) sp[t + j * 256] = carry[j];
#pragma unroll
    for (int j = 0; j < 32; j++) carry[j] = carry[j] * dec + raw[j];
  }
}

// ---------------- Y = Y_off + Y_diag + D*x  per (b,c,h); writes Y IN PLACE over states ----------------
__global__ __launch_bounds__(256) void k_ssd_y(
    const unsigned short* __restrict__ xBC, const float* __restrict__ dt,
    float* __restrict__ states, const float* __restrict__ cbuf,
    const float* __restrict__ A_log, const float* __restrict__ Dv) {
  int id = blockIdx.x;
  int h = id & 63, bc = id >> 6;
  int row0 = bc * CHUNK;
  int t = threadIdx.x;
  __shared__ float Acum[128];
  __shared__ float Ssm[64 * 132];
  __shared__ float Ct[32 * 129];
  __shared__ float Xst[32 * 68];
  __shared__ float Ms[32 * 33];
  float Ah = -expf(A_log[h]);
  if (t < 128) Acum[t] = dt[(size_t)(row0 + t) * 64 + h] * Ah;
  __syncthreads();
  for (int off = 1; off < 128; off <<= 1) {
    float v = 0.f;
    bool act = (t < 128) && (t >= off);
    if (act) v = Acum[t - off];
    __syncthreads();
    if (act) Acum[t] += v;
    __syncthreads();
  }
  float* sp = states + (size_t)id * 8192;
  // Load ENTIRE state slice to LDS before any in-place overwrite.
  for (int i = t; i < 8192; i += 256) {
    int p = i >> 7, n = i & 127;
    Ssm[p * 132 + n] = sp[i];
  }
  int lg = t & 31, p0 = (t >> 5) * 8;
  float Dh = Dv[h];
  for (int lt = 0; lt < 4; lt++) {
    __syncthreads();
    for (int i = t; i < 32 * 128; i += 256) {
      int l = i >> 7, n = i & 127;
      Ct[l * 129 + n] = bf2f(xBC[(size_t)(row0 + lt * 32 + l) * CONVDIM + COFF + n])
                      * expf(Acum[lt * 32 + l]);
    }
    __syncthreads();
    float acc[8];
#pragma unroll
    for (int j = 0; j < 8; j++) acc[j] = 0.f;
    // Y_off: sum_n C[l,n]*exp(Acum[l]) * S_in[p,n]
    for (int n4 = 0; n4 < 128; n4 += 4) {
      float cv0 = Ct[lg * 129 + n4];
      float cv1 = Ct[lg * 129 + n4 + 1];
      float cv2 = Ct[lg * 129 + n4 + 2];
      float cv3 = Ct[lg * 129 + n4 + 3];
#pragma unroll
      for (int pi = 0; pi < 8; pi++) {
        float4 sv = *(const float4*)&Ssm[(p0 + pi) * 132 + n4];
        acc[pi] += cv0 * sv.x + cv1 * sv.y + cv2 * sv.z + cv3 * sv.w;
      }
    }
    // Y_diag: sum_{s<=l} CB[l,s]*exp(Acum[l]-Acum[s]) * x[s,p]*dt[s]
    for (int st = 0; st <= lt; st++) {
      __syncthreads();
      for (int i = t; i < 32 * 32; i += 256) {
        int l = i >> 5, s2 = i & 31;
        int gl = lt * 32 + l, gs = st * 32 + s2;
        float v = 0.f;
        if (gs <= gl)
          v = cbuf[((size_t)bc * 128 + gl) * 128 + gs] * expf(Acum[gl] - Acum[gs]);
        Ms[l * 33 + s2] = v;
      }
      for (int i = t; i < 32 * 64; i += 256) {
        int s2 = i >> 6, p = i & 63;
        int gs = st * 32 + s2;
        Xst[s2 * 68 + p] = bf2f(xBC[(size_t)(row0 + gs) * CONVDIM + h * HEADDIM + p])
                         * dt[(size_t)(row0 + gs) * 64 + h];
      }
      __syncthreads();
      for (int s2 = 0; s2 < 32; s2++) {
        float mv = Ms[lg * 33 + s2];
        float4 x0 = *(const float4*)&Xst[s2 * 68 + p0];
        float4 x1 = *(const float4*)&Xst[s2 * 68 + p0 + 4];
        acc[0] += mv * x0.x; acc[1] += mv * x0.y; acc[2] += mv * x0.z; acc[3] += mv * x0.w;
        acc[4] += mv * x1.x; acc[5] += mv * x1.y; acc[6] += mv * x1.z; acc[7] += mv * x1.w;
      }
    }
    int gl = lt * 32 + lg;
    size_t xrow = (size_t)(row0 + gl) * CONVDIM + h * HEADDIM;
#pragma unroll
    for (int pi = 0; pi < 8; pi++) {
      float xv = bf2f(xBC[xrow + p0 + pi]);
      sp[gl * 64 + p0 + pi] = acc[pi] + Dh * xv;   // Y in place, layout [l_local][p]
    }
  }
}

// ---------------- gate (silu(z)), RMS norm, scale, -> bf16 ----------------
__global__ __launch_bounds__(256) void k_gate_rms(
    const float* __restrict__ Yst, const unsigned short* __restrict__ zx,
    const float* __restrict__ norm_w, unsigned short* __restrict__ ybf) {
  int row = blockIdx.x, t = threadIdx.x;
  int bc = row >> 7, ll = row & 127;
  float vals[16];
  float ss = 0.f;
#pragma unroll
  for (int j = 0; j < 16; j++) {
    int d = t + j * 256;
    int h = d >> 6, p = d & 63;
    float yv = Yst[(((size_t)bc * 64 + h) * 8192) + ll * 64 + p];
    float z = bf2f(zx[(size_t)row * DINP + d]);
    float g = yv * (z / (1.f + expf(-z)));
    vals[j] = g;
    ss += g * g;
  }
#pragma unroll
  for (int off = 32; off > 0; off >>= 1) ss += __shfl_down(ss, off, 64);
  __shared__ float red[4];
  if ((t & 63) == 0) red[t >> 6] = ss;
  __syncthreads();
  float tot = red[0] + red[1] + red[2] + red[3];
  float rms = rsqrtf(tot / (float)D_SSM + 1e-5f);
#pragma unroll
  for (int j = 0; j < 16; j++) {
    int d = t + j * 256;
    ybf[(size_t)row * D_SSM + d] = f2bf(vals[j] * rms * norm_w[d]);
  }
}

// ---------------- out += out[:, ::-1, :] (in place, pairwise) ----------------
__global__ void k_flipadd(float* __restrict__ out) {
  int id = blockIdx.x * 256 + threadIdx.x;   // B * (L/2) * D_MODEL
  int d = id & 2047;
  int rem = id >> 11;
  int l = rem & 1023;
  int b = rem >> 10;
  size_t i1 = ((size_t)b * LSEQ + l) * D_MODEL + d;
  size_t i2 = ((size_t)b * LSEQ + (LSEQ - 1 - l)) * D_MODEL + d;
  float a = out[i1], c = out[i2];
  out[i1] = a + c;
  out[i2] = a + c;
}

// ---------------- launch ----------------
extern "C" void kernel_launch(void* const* d_in, const int* in_sizes, int n_in,
                              void* d_out, int out_size, void* d_ws, size_t ws_size,
                              hipStream_t stream) {
  if (ws_size < WS_NEED) return;   // fail cleanly (absmax) instead of OOB-faulting
  const float* u       = (const float*)d_in[0];
  const float* W_in    = (const float*)d_in[1];
  const float* conv_w  = (const float*)d_in[2];
  const float* conv_b  = (const float*)d_in[3];
  const float* dt_bias = (const float*)d_in[4];
  const float* A_log   = (const float*)d_in[5];
  const float* Dv      = (const float*)d_in[6];
  const float* norm_w  = (const float*)d_in[7];
  const float* W_out   = (const float*)d_in[8];
  float* out = (float*)d_out;
  char* ws = (char*)d_ws;

  unsigned short* winb = (unsigned short*)(ws + OFF_WIN); // later: y bf16
  unsigned short* ub   = (unsigned short*)(ws + OFF_UB);  // later: W_out bf16
  unsigned short* zx   = (unsigned short*)(ws + OFF_ZX);
  unsigned short* xbc  = (unsigned short*)(ws + OFF_XBC);
  float* dtb  = (float*)(ws + OFF_DT);
  float* st   = (float*)(ws + OFF_ST);   // states, then Y in place
  float* cbuf = (float*)(ws + OFF_CB);
  float* dAs  = (float*)(ws + OFF_DAS);

  // convert u and W_in (pad W_in rows 8512->8576 with zeros)
  k_cvt4<<<2097152 / 256, 256, 0, stream>>>((const float4*)u, (ushort4*)ub, 2097152, 2097152);
  k_cvt4<<<4390912 / 256, 256, 0, stream>>>((const float4*)W_in, (ushort4*)winb, 4390912, 4358144);
  // in-projection GEMM: zx[BL][DINP] = u[BL][2048] * W_in^T   (bf16 out)
  k_gemm_bt<true><<<dim3(DINP / 128, BL / 128), 256, 0, stream>>>(ub, winb, zx, BL, DINP, D_MODEL);
  // W_out -> bf16 (reuses u_bf16 region, dead after GEMM1)
  k_cvt4<<<2097152 / 256, 256, 0, stream>>>((const float4*)W_out, (ushort4*)ub, 2097152, 2097152);
  // dt and conv
  k_dt<<<BL * 64 / 256, 256, 0, stream>>>(zx, dt_bias, dtb);
  k_conv<<<(BL * CONVDIM) / 256, 256, 0, stream>>>(zx, conv_w, conv_b, xbc);
  // SSD
  k_cb<<<B_SZ * NCH, 256, 0, stream>>>(xbc, cbuf);
  k_states<<<B_SZ * NCH * NHEADS, 256, 0, stream>>>(xbc, dtb, A_log, st, dAs);
  k_scan<<<B_SZ * NHEADS, 256, 0, stream>>>(st, dAs);
  k_ssd_y<<<B_SZ * NCH * NHEADS, 256, 0, stream>>>(xbc, dtb, st, cbuf, A_log, Dv);
  // gate + RMS norm -> bf16 (into W_in bf16 region, dead after GEMM1)
  k_gate_rms<<<BL, 256, 0, stream>>>(st, zx, norm_w, winb);
  // out-projection GEMM into d_out (fp32 out)
  k_gemm_bt<false><<<dim3(D_MODEL / 128, BL / 128), 256, 0, stream>>>(winb, ub, out, BL, D_MODEL, D_SSM);
  // out += flipped(out)
  k_flipadd<<<(B_SZ * (LSEQ / 2) * D_MODEL) / 256, 256, 0, stream>>>(out);
}

// Round 3
// 973.908 us; speedup vs baseline: 5.9472x; 5.9472x over previous
//
#include <hip/hip_runtime.h>

// ---------------- problem constants ----------------
constexpr int B_SZ = 2, LSEQ = 2048, D_MODEL = 2048;
constexpr int D_SSM = 4096, D_STATE = 128, NHEADS = 64, HEADDIM = 64;
constexpr int CHUNK = 128;
constexpr int NCH = LSEQ / CHUNK;             // 16
constexpr int BL = B_SZ * LSEQ;               // 4096 token rows
constexpr int DIN = 2 * D_SSM + 2 * D_STATE + NHEADS; // 8512
constexpr int DINP = 8576;                    // padded to 67*128
constexpr int CONVDIM = D_SSM + 2 * D_STATE;  // 4352
constexpr int BOFF = D_SSM;                   // B offset inside xBC_conv
constexpr int COFF = D_SSM + D_STATE;         // C offset inside xBC_conv

// ---------------- workspace layout (bytes) — total ~218 MiB ----------------
constexpr size_t OFF_WIN = 0;                                      // W_in bf16 -> later y bf16
constexpr size_t OFF_UB  = OFF_WIN + (size_t)DINP * D_MODEL * 2;   // u bf16 -> later W_out bf16
constexpr size_t OFF_ZX  = OFF_UB + (size_t)BL * D_MODEL * 2;      // zxbcdt bf16 (BL x DINP)
constexpr size_t OFF_XBC = OFF_ZX + (size_t)BL * DINP * 2;         // conv output bf16 (BL x 4352)
constexpr size_t OFF_DT  = OFF_XBC + (size_t)BL * CONVDIM * 2;     // dt fp32 (BL x 64)
constexpr size_t OFF_ST  = OFF_DT + (size_t)BL * NHEADS * 4;       // states fp32 (2048 x 8192), reused as Y
constexpr size_t OFF_CB  = OFF_ST + (size_t)B_SZ * NCH * NHEADS * HEADDIM * D_STATE * 4;
constexpr size_t OFF_DAS = OFF_CB + (size_t)B_SZ * NCH * CHUNK * CHUNK * 4;
constexpr size_t WS_NEED = OFF_DAS + (size_t)B_SZ * NCH * NHEADS * 4 + 4096;

typedef float f32x4 __attribute__((ext_vector_type(4)));
typedef __bf16 bf16x8 __attribute__((ext_vector_type(8)));

__device__ __forceinline__ unsigned short f2bf(float f) {
  unsigned int x = __float_as_uint(f);
  x += 0x7fffu + ((x >> 16) & 1u);   // round-to-nearest-even
  return (unsigned short)(x >> 16);
}
__device__ __forceinline__ float bf2f(unsigned short u) {
  return __uint_as_float(((unsigned int)u) << 16);
}

// ---------------- fp32 -> bf16 convert (with zero padding past nsrc4) ----------------
__global__ void k_cvt4(const float4* __restrict__ src, ushort4* __restrict__ dst,
                       int n4, int nsrc4) {
  int i = blockIdx.x * 256 + threadIdx.x;
  if (i >= n4) return;
  float4 v = make_float4(0.f, 0.f, 0.f, 0.f);
  if (i < nsrc4) v = src[i];
  ushort4 o;
  o.x = f2bf(v.x); o.y = f2bf(v.y); o.z = f2bf(v.z); o.w = f2bf(v.w);
  dst[i] = o;
}

// ---------------- bf16 MFMA GEMM: C[M][N] = A[M][K] * B[N][K]^T ----------------
template <bool OUT_BF16>
__global__ __launch_bounds__(256, 2) void k_gemm_bt(
    const unsigned short* __restrict__ A, const unsigned short* __restrict__ Bm,
    void* __restrict__ Cv, int M, int N, int K) {
  __shared__ __align__(16) unsigned short As[128 * 32];
  __shared__ __align__(16) unsigned short Bs[128 * 32];
  int t = threadIdx.x;
  int m0 = blockIdx.y * 128, n0 = blockIdx.x * 128;
  int w = t >> 6, lane = t & 63;
  int wm = (w >> 1) * 64, wn = (w & 1) * 64;
  int lr = lane & 15, lk = (lane >> 4) * 8;
  f32x4 acc[4][4] = {};
  int sr = t >> 2, sc = (t & 3) * 8;
  const unsigned short* Ap = A + (size_t)(m0 + sr) * K + sc;
  const unsigned short* Bp = Bm + (size_t)(n0 + sr) * K + sc;
  for (int k0 = 0; k0 < K; k0 += 32) {
    int4 a0 = *(const int4*)(Ap + k0);
    int4 a1 = *(const int4*)(Ap + (size_t)64 * K + k0);
    int4 b0 = *(const int4*)(Bp + k0);
    int4 b1 = *(const int4*)(Bp + (size_t)64 * K + k0);
    __syncthreads();
    *(int4*)&As[sr * 32 + sc] = a0;
    *(int4*)&As[(sr + 64) * 32 + sc] = a1;
    *(int4*)&Bs[sr * 32 + sc] = b0;
    *(int4*)&Bs[(sr + 64) * 32 + sc] = b1;
    __syncthreads();
    bf16x8 af[4], bfv[4];
#pragma unroll
    for (int i = 0; i < 4; i++) af[i]  = *(const bf16x8*)&As[(wm + i * 16 + lr) * 32 + lk];
#pragma unroll
    for (int i = 0; i < 4; i++) bfv[i] = *(const bf16x8*)&Bs[(wn + i * 16 + lr) * 32 + lk];
#pragma unroll
    for (int mi = 0; mi < 4; mi++)
#pragma unroll
      for (int ni = 0; ni < 4; ni++)
        acc[mi][ni] = __builtin_amdgcn_mfma_f32_16x16x32_bf16(af[mi], bfv[ni], acc[mi][ni], 0, 0, 0);
  }
  int orow = (lane >> 4) * 4, ocol = lane & 15;
#pragma unroll
  for (int mi = 0; mi < 4; mi++)
#pragma unroll
    for (int ni = 0; ni < 4; ni++) {
      int r0 = m0 + wm + mi * 16 + orow;
      int c0 = n0 + wn + ni * 16 + ocol;
#pragma unroll
      for (int r = 0; r < 4; r++) {
        if (OUT_BF16)
          ((unsigned short*)Cv)[(size_t)(r0 + r) * N + c0] = f2bf(acc[mi][ni][r]);
        else
          ((float*)Cv)[(size_t)(r0 + r) * N + c0] = acc[mi][ni][r];
      }
    }
}

// ---------------- dt = softplus(raw + dt_bias) ----------------
__global__ void k_dt(const unsigned short* __restrict__ zx, const float* __restrict__ dt_bias,
                     float* __restrict__ dt) {
  int id = blockIdx.x * 256 + threadIdx.x;   // BL*64
  int row = id >> 6, h = id & 63;
  float x = bf2f(zx[(size_t)row * DINP + (2 * D_SSM + 2 * D_STATE) + h]) + dt_bias[h];
  dt[id] = (x > 20.f) ? x : log1pf(expf(x));
}

// ---------------- causal depthwise conv (width 3) + bias + SiLU ----------------
__global__ void k_conv(const unsigned short* __restrict__ zx, const float* __restrict__ cw,
                       const float* __restrict__ cbv, unsigned short* __restrict__ out) {
  int id = blockIdx.x * 256 + threadIdx.x;
  if (id >= BL * CONVDIM) return;
  int c = id % CONVDIM;
  int row = id / CONVDIM;
  int b = row >> 11, l = row & 2047;
  float acc = cbv[c];
#pragma unroll
  for (int k = 0; k < 3; k++) {
    int ls = l + k - 2;
    if (ls >= 0)
      acc += bf2f(zx[(size_t)(b * LSEQ + ls) * DINP + D_SSM + c]) * cw[c * 3 + k];
  }
  out[(size_t)row * CONVDIM + c] = f2bf(acc / (1.f + expf(-acc)));
}

// ---------------- CB[l][s] = C[l] . B[s]  per (b,c) chunk (head-independent) ----------------
__global__ __launch_bounds__(256) void k_cb(const unsigned short* __restrict__ xBC,
                                            float* __restrict__ cbuf) {
  int bc = blockIdx.x;          // b*16 + c
  int row0 = bc * CHUNK;
  int t = threadIdx.x;
  __shared__ float Cs[32 * 132];
  int s = t & 127, lh = t >> 7; // lh in {0,1}
  for (int lt = 0; lt < 4; lt++) {
    __syncthreads();
    for (int i = t; i < 32 * 128; i += 256) {
      int l = i >> 7, n = i & 127;
      Cs[l * 132 + n] = bf2f(xBC[(size_t)(row0 + lt * 32 + l) * CONVDIM + COFF + n]);
    }
    __syncthreads();
    float acc[16];
#pragma unroll
    for (int j = 0; j < 16; j++) acc[j] = 0.f;
    const unsigned short* bp = xBC + (size_t)(row0 + s) * CONVDIM + BOFF;
    for (int n4 = 0; n4 < 128; n4 += 4) {
      ushort4 bu = *(const ushort4*)(bp + n4);
      float b0 = bf2f(bu.x), b1 = bf2f(bu.y), b2 = bf2f(bu.z), b3 = bf2f(bu.w);
#pragma unroll
      for (int li = 0; li < 16; li++) {
        float4 cv = *(const float4*)&Cs[(lh * 16 + li) * 132 + n4];
        acc[li] += b0 * cv.x + b1 * cv.y + b2 * cv.z + b3 * cv.w;
      }
    }
#pragma unroll
    for (int li = 0; li < 16; li++) {
      int gl = lt * 32 + lh * 16 + li;
      cbuf[((size_t)bc * 128 + gl) * 128 + s] = acc[li];
    }
  }
}

// ---------------- per-chunk raw states via MFMA ----------------
// S[p][n] = sum_l (x[l,p]*dt[l]) * (B[l,n]*exp(Alast-Acum[l]))
// Staged transposed in LDS as [row][l ^ (row&24)] (XOR swizzle keeps 8-runs
// contiguous for ds_read_b128 while breaking transpose-write bank collisions).
__global__ __launch_bounds__(256, 2) void k_states(
    const unsigned short* __restrict__ xBC, const float* __restrict__ dt,
    const float* __restrict__ A_log, float* __restrict__ states,
    float* __restrict__ dAsum) {
  constexpr int LP = 136;   // l-stride (elements); 136*2B = 272 = 16*17 -> 16B row align
  int id = blockIdx.x; int h = id & 63; int bc = id >> 6; int row0 = bc * CHUNK;
  int t = threadIdx.x;
  __shared__ float Acum[128];
  __shared__ float wdec[128];
  __shared__ __align__(16) unsigned short Bt[128 * LP]; // [n][l^]
  __shared__ __align__(16) unsigned short Xt[64 * LP];  // [p][l^]
  float Ah = -expf(A_log[h]);
  if (t < 128) Acum[t] = dt[(size_t)(row0 + t) * 64 + h] * Ah;
  __syncthreads();
  for (int off = 1; off < 128; off <<= 1) {
    float v = 0.f;
    bool act = (t < 128) && (t >= off);
    if (act) v = Acum[t - off];
    __syncthreads();
    if (act) Acum[t] += v;
    __syncthreads();
  }
  float Alast = Acum[127];
  if (t < 128) wdec[t] = expf(Alast - Acum[t]);
  if (t == 0) dAsum[id] = Alast;
  __syncthreads();
  // stage Bt (128 l x 128 n, transposed)
  for (int i = t; i < 16 * 128; i += 256) {
    int l = i >> 4, n0 = (i & 15) * 8;
    const unsigned short* src = xBC + (size_t)(row0 + l) * CONVDIM + BOFF + n0;
    ushort4 v0 = *(const ushort4*)src;
    ushort4 v1 = *(const ushort4*)(src + 4);
    float wl = wdec[l];
    int ls = l ^ (n0 & 24);
    Bt[(n0 + 0) * LP + ls] = f2bf(bf2f(v0.x) * wl);
    Bt[(n0 + 1) * LP + ls] = f2bf(bf2f(v0.y) * wl);
    Bt[(n0 + 2) * LP + ls] = f2bf(bf2f(v0.z) * wl);
    Bt[(n0 + 3) * LP + ls] = f2bf(bf2f(v0.w) * wl);
    Bt[(n0 + 4) * LP + ls] = f2bf(bf2f(v1.x) * wl);
    Bt[(n0 + 5) * LP + ls] = f2bf(bf2f(v1.y) * wl);
    Bt[(n0 + 6) * LP + ls] = f2bf(bf2f(v1.z) * wl);
    Bt[(n0 + 7) * LP + ls] = f2bf(bf2f(v1.w) * wl);
  }
  // stage Xt (128 l x 64 p, transposed), scaled by dt
  for (int i = t; i < 8 * 128; i += 256) {
    int l = i >> 3, p0 = (i & 7) * 8;
    const unsigned short* src = xBC + (size_t)(row0 + l) * CONVDIM + h * HEADDIM + p0;
    ushort4 v0 = *(const ushort4*)src;
    ushort4 v1 = *(const ushort4*)(src + 4);
    float dl = dt[(size_t)(row0 + l) * 64 + h];
    int ls = l ^ (p0 & 24);
    Xt[(p0 + 0) * LP + ls] = f2bf(bf2f(v0.x) * dl);
    Xt[(p0 + 1) * LP + ls] = f2bf(bf2f(v0.y) * dl);
    Xt[(p0 + 2) * LP + ls] = f2bf(bf2f(v0.z) * dl);
    Xt[(p0 + 3) * LP + ls] = f2bf(bf2f(v0.w) * dl);
    Xt[(p0 + 4) * LP + ls] = f2bf(bf2f(v1.x) * dl);
    Xt[(p0 + 5) * LP + ls] = f2bf(bf2f(v1.y) * dl);
    Xt[(p0 + 6) * LP + ls] = f2bf(bf2f(v1.z) * dl);
    Xt[(p0 + 7) * LP + ls] = f2bf(bf2f(v1.w) * dl);
  }
  __syncthreads();
  int w = t >> 6, lane = t & 63;
  int lr = lane & 15, lk = (lane >> 4) * 8;
  int pp = w * 16 + lr;            // wave w covers p in [w*16, w*16+16)
  f32x4 acc[8] = {};
  for (int k0 = 0; k0 < 128; k0 += 32) {
    bf16x8 af = *(const bf16x8*)&Xt[pp * LP + ((k0 + lk) ^ (pp & 24))];
#pragma unroll
    for (int nt = 0; nt < 8; nt++) {
      int nn = nt * 16 + lr;
      bf16x8 bfr = *(const bf16x8*)&Bt[nn * LP + ((k0 + lk) ^ (nn & 24))];
      acc[nt] = __builtin_amdgcn_mfma_f32_16x16x32_bf16(af, bfr, acc[nt], 0, 0, 0);
    }
  }
  float* sp = states + (size_t)id * 8192;
  int orow = (lane >> 4) * 4, ocol = lane & 15;
#pragma unroll
  for (int nt = 0; nt < 8; nt++)
#pragma unroll
    for (int r = 0; r < 4; r++)
      sp[(w * 16 + orow + r) * 128 + nt * 16 + ocol] = acc[nt][r];
}

// ---------------- inter-chunk recurrence (in-place: raw states -> entering states) ----------------
__global__ __launch_bounds__(256) void k_scan(float* __restrict__ states,
                                              const float* __restrict__ dAsum) {
  int bh = blockIdx.x; int h = bh & 63; int b = bh >> 6;
  int t = threadIdx.x;
  float carry[32];
#pragma unroll
  for (int j = 0; j < 32; j++) carry[j] = 0.f;
  for (int c = 0; c < NCH; c++) {
    int bc = b * NCH + c;
    float* sp = states + ((size_t)bc * 64 + h) * 8192;
    float dec = expf(dAsum[bc * 64 + h]);
    float raw[32];
#pragma unroll
    for (int j = 0; j < 32; j++) raw[j] = sp[t + j * 256];
#pragma unroll
    for (int j = 0; j < 32; j++) sp[t + j * 256] = carry[j];
#pragma unroll
    for (int j = 0; j < 32; j++) carry[j] = carry[j] * dec + raw[j];
  }
}

// ---------------- Y = Y_off + Y_diag + D*x  per (b,c,h); writes Y IN PLACE over states ----------------
__global__ __launch_bounds__(256) void k_ssd_y(
    const unsigned short* __restrict__ xBC, const float* __restrict__ dt,
    float* __restrict__ states, const float* __restrict__ cbuf,
    const float* __restrict__ A_log, const float* __restrict__ Dv) {
  int id = blockIdx.x;
  int h = id & 63, bc = id >> 6;
  int row0 = bc * CHUNK;
  int t = threadIdx.x;
  __shared__ float Acum[128];
  __shared__ float Ssm[64 * 132];
  __shared__ float Ct[32 * 129];
  __shared__ float Xst[32 * 68];
  __shared__ float Ms[32 * 33];
  float Ah = -expf(A_log[h]);
  if (t < 128) Acum[t] = dt[(size_t)(row0 + t) * 64 + h] * Ah;
  __syncthreads();
  for (int off = 1; off < 128; off <<= 1) {
    float v = 0.f;
    bool act = (t < 128) && (t >= off);
    if (act) v = Acum[t - off];
    __syncthreads();
    if (act) Acum[t] += v;
    __syncthreads();
  }
  float* sp = states + (size_t)id * 8192;
  // Load ENTIRE state slice to LDS before any in-place overwrite.
  for (int i = t; i < 8192; i += 256) {
    int p = i >> 7, n = i & 127;
    Ssm[p * 132 + n] = sp[i];
  }
  int lg = t & 31, p0 = (t >> 5) * 8;
  float Dh = Dv[h];
  for (int lt = 0; lt < 4; lt++) {
    __syncthreads();
    for (int i = t; i < 32 * 128; i += 256) {
      int l = i >> 7, n = i & 127;
      Ct[l * 129 + n] = bf2f(xBC[(size_t)(row0 + lt * 32 + l) * CONVDIM + COFF + n])
                      * expf(Acum[lt * 32 + l]);
    }
    __syncthreads();
    float acc[8];
#pragma unroll
    for (int j = 0; j < 8; j++) acc[j] = 0.f;
    // Y_off: sum_n C[l,n]*exp(Acum[l]) * S_in[p,n]
    for (int n4 = 0; n4 < 128; n4 += 4) {
      float cv0 = Ct[lg * 129 + n4];
      float cv1 = Ct[lg * 129 + n4 + 1];
      float cv2 = Ct[lg * 129 + n4 + 2];
      float cv3 = Ct[lg * 129 + n4 + 3];
#pragma unroll
      for (int pi = 0; pi < 8; pi++) {
        float4 sv = *(const float4*)&Ssm[(p0 + pi) * 132 + n4];
        acc[pi] += cv0 * sv.x + cv1 * sv.y + cv2 * sv.z + cv3 * sv.w;
      }
    }
    // Y_diag: sum_{s<=l} CB[l,s]*exp(Acum[l]-Acum[s]) * x[s,p]*dt[s]
    for (int st = 0; st <= lt; st++) {
      __syncthreads();
      for (int i = t; i < 32 * 32; i += 256) {
        int l = i >> 5, s2 = i & 31;
        int gl = lt * 32 + l, gs = st * 32 + s2;
        float v = 0.f;
        if (gs <= gl)
          v = cbuf[((size_t)bc * 128 + gl) * 128 + gs] * expf(Acum[gl] - Acum[gs]);
        Ms[l * 33 + s2] = v;
      }
      for (int i = t; i < 32 * 64; i += 256) {
        int s2 = i >> 6, p = i & 63;
        int gs = st * 32 + s2;
        Xst[s2 * 68 + p] = bf2f(xBC[(size_t)(row0 + gs) * CONVDIM + h * HEADDIM + p])
                         * dt[(size_t)(row0 + gs) * 64 + h];
      }
      __syncthreads();
      for (int s2 = 0; s2 < 32; s2++) {
        float mv = Ms[lg * 33 + s2];
        float4 x0 = *(const float4*)&Xst[s2 * 68 + p0];
        float4 x1 = *(const float4*)&Xst[s2 * 68 + p0 + 4];
        acc[0] += mv * x0.x; acc[1] += mv * x0.y; acc[2] += mv * x0.z; acc[3] += mv * x0.w;
        acc[4] += mv * x1.x; acc[5] += mv * x1.y; acc[6] += mv * x1.z; acc[7] += mv * x1.w;
      }
    }
    int gl = lt * 32 + lg;
    size_t xrow = (size_t)(row0 + gl) * CONVDIM + h * HEADDIM;
#pragma unroll
    for (int pi = 0; pi < 8; pi++) {
      float xv = bf2f(xBC[xrow + p0 + pi]);
      sp[gl * 64 + p0 + pi] = acc[pi] + Dh * xv;   // Y in place, layout [l_local][p]
    }
  }
}

// ---------------- gate (silu(z)), RMS norm, scale, -> bf16 ----------------
__global__ __launch_bounds__(256) void k_gate_rms(
    const float* __restrict__ Yst, const unsigned short* __restrict__ zx,
    const float* __restrict__ norm_w, unsigned short* __restrict__ ybf) {
  int row = blockIdx.x, t = threadIdx.x;
  int bc = row >> 7, ll = row & 127;
  float vals[16];
  float ss = 0.f;
#pragma unroll
  for (int j = 0; j < 16; j++) {
    int d = t + j * 256;
    int h = d >> 6, p = d & 63;
    float yv = Yst[(((size_t)bc * 64 + h) * 8192) + ll * 64 + p];
    float z = bf2f(zx[(size_t)row * DINP + d]);
    float g = yv * (z / (1.f + expf(-z)));
    vals[j] = g;
    ss += g * g;
  }
#pragma unroll
  for (int off = 32; off > 0; off >>= 1) ss += __shfl_down(ss, off, 64);
  __shared__ float red[4];
  if ((t & 63) == 0) red[t >> 6] = ss;
  __syncthreads();
  float tot = red[0] + red[1] + red[2] + red[3];
  float rms = rsqrtf(tot / (float)D_SSM + 1e-5f);
#pragma unroll
  for (int j = 0; j < 16; j++) {
    int d = t + j * 256;
    ybf[(size_t)row * D_SSM + d] = f2bf(vals[j] * rms * norm_w[d]);
  }
}

// ---------------- out += out[:, ::-1, :] (in place, pairwise) ----------------
__global__ void k_flipadd(float* __restrict__ out) {
  int id = blockIdx.x * 256 + threadIdx.x;   // B * (L/2) * D_MODEL
  int d = id & 2047;
  int rem = id >> 11;
  int l = rem & 1023;
  int b = rem >> 10;
  size_t i1 = ((size_t)b * LSEQ + l) * D_MODEL + d;
  size_t i2 = ((size_t)b * LSEQ + (LSEQ - 1 - l)) * D_MODEL + d;
  float a = out[i1], c = out[i2];
  out[i1] = a + c;
  out[i2] = a + c;
}

// ---------------- launch ----------------
extern "C" void kernel_launch(void* const* d_in, const int* in_sizes, int n_in,
                              void* d_out, int out_size, void* d_ws, size_t ws_size,
                              hipStream_t stream) {
  if (ws_size < WS_NEED) return;   // fail cleanly instead of OOB-faulting
  const float* u       = (const float*)d_in[0];
  const float* W_in    = (const float*)d_in[1];
  const float* conv_w  = (const float*)d_in[2];
  const float* conv_b  = (const float*)d_in[3];
  const float* dt_bias = (const float*)d_in[4];
  const float* A_log   = (const float*)d_in[5];
  const float* Dv      = (const float*)d_in[6];
  const float* norm_w  = (const float*)d_in[7];
  const float* W_out   = (const float*)d_in[8];
  float* out = (float*)d_out;
  char* ws = (char*)d_ws;

  unsigned short* winb = (unsigned short*)(ws + OFF_WIN); // later: y bf16
  unsigned short* ub   = (unsigned short*)(ws + OFF_UB);  // later: W_out bf16
  unsigned short* zx   = (unsigned short*)(ws + OFF_ZX);
  unsigned short* xbc  = (unsigned short*)(ws + OFF_XBC);
  float* dtb  = (float*)(ws + OFF_DT);
  float* st   = (float*)(ws + OFF_ST);   // states, then Y in place
  float* cbuf = (float*)(ws + OFF_CB);
  float* dAs  = (float*)(ws + OFF_DAS);

  // convert u and W_in (pad W_in rows 8512->8576 with zeros)
  k_cvt4<<<2097152 / 256, 256, 0, stream>>>((const float4*)u, (ushort4*)ub, 2097152, 2097152);
  k_cvt4<<<4390912 / 256, 256, 0, stream>>>((const float4*)W_in, (ushort4*)winb, 4390912, 4358144);
  // in-projection GEMM: zx[BL][DINP] = u[BL][2048] * W_in^T   (bf16 out)
  k_gemm_bt<true><<<dim3(DINP / 128, BL / 128), 256, 0, stream>>>(ub, winb, zx, BL, DINP, D_MODEL);
  // W_out -> bf16 (reuses u_bf16 region, dead after GEMM1)
  k_cvt4<<<2097152 / 256, 256, 0, stream>>>((const float4*)W_out, (ushort4*)ub, 2097152, 2097152);
  // dt and conv
  k_dt<<<BL * 64 / 256, 256, 0, stream>>>(zx, dt_bias, dtb);
  k_conv<<<(BL * CONVDIM) / 256, 256, 0, stream>>>(zx, conv_w, conv_b, xbc);
  // SSD
  k_cb<<<B_SZ * NCH, 256, 0, stream>>>(xbc, cbuf);
  k_states<<<B_SZ * NCH * NHEADS, 256, 0, stream>>>(xbc, dtb, A_log, st, dAs);
  k_scan<<<B_SZ * NHEADS, 256, 0, stream>>>(st, dAs);
  k_ssd_y<<<B_SZ * NCH * NHEADS, 256, 0, stream>>>(xbc, dtb, st, cbuf, A_log, Dv);
  // gate + RMS norm -> bf16 (into W_in bf16 region, dead after GEMM1)
  k_gate_rms<<<BL, 256, 0, stream>>>(st, zx, norm_w, winb);
  // out-projection GEMM into d_out (fp32 out)
  k_gemm_bt<false><<<dim3(D_MODEL / 128, BL / 128), 256, 0, stream>>>(winb, ub, out, BL, D_MODEL, D_SSM);
  // out += flipped(out)
  k_flipadd<<<(B_SZ * (LSEQ / 2) * D_MODEL) / 256, 256, 0, stream>>>(out);
}

// Round 4
// 727.942 us; speedup vs baseline: 7.9567x; 1.3379x over previous
//
#include <hip/hip_runtime.h>

// ---------------- problem constants ----------------
constexpr int B_SZ = 2, LSEQ = 2048, D_MODEL = 2048;
constexpr int D_SSM = 4096, D_STATE = 128, NHEADS = 64, HEADDIM = 64;
constexpr int CHUNK = 128;
constexpr int NCH = LSEQ / CHUNK;             // 16
constexpr int BL = B_SZ * LSEQ;               // 4096 token rows
constexpr int DIN = 2 * D_SSM + 2 * D_STATE + NHEADS; // 8512
constexpr int DINP = 8576;                    // padded to 67*128
constexpr int CONVDIM = D_SSM + 2 * D_STATE;  // 4352
constexpr int BOFF = D_SSM;                   // B offset inside xBC_conv
constexpr int COFF = D_SSM + D_STATE;         // C offset inside xBC_conv

// ---------------- workspace layout (bytes) — total ~218 MiB ----------------
constexpr size_t OFF_WIN = 0;                                      // W_in bf16 -> later y bf16
constexpr size_t OFF_UB  = OFF_WIN + (size_t)DINP * D_MODEL * 2;   // u bf16 -> later W_out bf16
constexpr size_t OFF_ZX  = OFF_UB + (size_t)BL * D_MODEL * 2;      // zxbcdt bf16 (BL x DINP)
constexpr size_t OFF_XBC = OFF_ZX + (size_t)BL * DINP * 2;         // conv output bf16 (BL x 4352)
constexpr size_t OFF_DT  = OFF_XBC + (size_t)BL * CONVDIM * 2;     // dt fp32 (BL x 64)
constexpr size_t OFF_ST  = OFF_DT + (size_t)BL * NHEADS * 4;       // states fp32 (2048 x 8192), reused as Y
constexpr size_t OFF_CB  = OFF_ST + (size_t)B_SZ * NCH * NHEADS * HEADDIM * D_STATE * 4;
constexpr size_t OFF_DAS = OFF_CB + (size_t)B_SZ * NCH * CHUNK * CHUNK * 4;
constexpr size_t WS_NEED = OFF_DAS + (size_t)B_SZ * NCH * NHEADS * 4 + 4096;

typedef float f32x4 __attribute__((ext_vector_type(4)));
typedef __bf16 bf16x8 __attribute__((ext_vector_type(8)));

__device__ __forceinline__ unsigned short f2bf(float f) {
  unsigned int x = __float_as_uint(f);
  x += 0x7fffu + ((x >> 16) & 1u);   // round-to-nearest-even
  return (unsigned short)(x >> 16);
}
__device__ __forceinline__ float bf2f(unsigned short u) {
  return __uint_as_float(((unsigned int)u) << 16);
}

// async global->LDS, 16 B per lane; LDS dest = wave-uniform base + lane*16
__device__ __forceinline__ void llds16(const unsigned short* g, unsigned short* l) {
  __builtin_amdgcn_global_load_lds(
      (const __attribute__((address_space(1))) unsigned int*)g,
      (__attribute__((address_space(3))) unsigned int*)l, 16, 0, 0);
}

// ---------------- fp32 -> bf16 convert (with zero padding past nsrc4) ----------------
__global__ void k_cvt4(const float4* __restrict__ src, ushort4* __restrict__ dst,
                       int n4, int nsrc4) {
  int i = blockIdx.x * 256 + threadIdx.x;
  if (i >= n4) return;
  float4 v = make_float4(0.f, 0.f, 0.f, 0.f);
  if (i < nsrc4) v = src[i];
  ushort4 o;
  o.x = f2bf(v.x); o.y = f2bf(v.y); o.z = f2bf(v.z); o.w = f2bf(v.w);
  dst[i] = o;
}

// ---------------- bf16 MFMA GEMM: C[M][N] = A[M][K] * B[N][K]^T ----------------
// 128x128 tile, 4 waves, BK=32, async global_load_lds staging (m97 structure).
template <bool OUT_BF16>
__global__ __launch_bounds__(256, 2) void k_gemm_bt(
    const unsigned short* __restrict__ A, const unsigned short* __restrict__ Bm,
    void* __restrict__ Cv, int M, int N, int K) {
  __shared__ __align__(16) unsigned short As[128 * 32];
  __shared__ __align__(16) unsigned short Bs[128 * 32];
  int t = threadIdx.x;
  int m0 = blockIdx.y * 128, n0 = blockIdx.x * 128;
  int w = t >> 6, lane = t & 63;
  int wm = (w >> 1) * 64, wn = (w & 1) * 64;
  int lr = lane & 15, lk = (lane >> 4) * 8;
  f32x4 acc[4][4] = {};
  // staging map: thread t covers row t>>2, cols (t&3)*8..+8  => LDS elem 8t (lane*16B)
  const unsigned short* Ap = A + (size_t)(m0 + (t >> 2)) * K + (t & 3) * 8;
  const unsigned short* Bp = Bm + (size_t)(n0 + (t >> 2)) * K + (t & 3) * 8;
  unsigned short* AsW0 = As + w * 512;
  unsigned short* AsW1 = As + 2048 + w * 512;
  unsigned short* BsW0 = Bs + w * 512;
  unsigned short* BsW1 = Bs + 2048 + w * 512;
  for (int k0 = 0; k0 < K; k0 += 32) {
    __syncthreads();
    llds16(Ap + k0, AsW0);
    llds16(Ap + (size_t)64 * K + k0, AsW1);
    llds16(Bp + k0, BsW0);
    llds16(Bp + (size_t)64 * K + k0, BsW1);
    __syncthreads();
    bf16x8 af[4], bfv[4];
#pragma unroll
    for (int i = 0; i < 4; i++) af[i]  = *(const bf16x8*)&As[(wm + i * 16 + lr) * 32 + lk];
#pragma unroll
    for (int i = 0; i < 4; i++) bfv[i] = *(const bf16x8*)&Bs[(wn + i * 16 + lr) * 32 + lk];
#pragma unroll
    for (int mi = 0; mi < 4; mi++)
#pragma unroll
      for (int ni = 0; ni < 4; ni++)
        acc[mi][ni] = __builtin_amdgcn_mfma_f32_16x16x32_bf16(af[mi], bfv[ni], acc[mi][ni], 0, 0, 0);
  }
  int orow = (lane >> 4) * 4, ocol = lane & 15;
#pragma unroll
  for (int mi = 0; mi < 4; mi++)
#pragma unroll
    for (int ni = 0; ni < 4; ni++) {
      int r0 = m0 + wm + mi * 16 + orow;
      int c0 = n0 + wn + ni * 16 + ocol;
#pragma unroll
      for (int r = 0; r < 4; r++) {
        if (OUT_BF16)
          ((unsigned short*)Cv)[(size_t)(r0 + r) * N + c0] = f2bf(acc[mi][ni][r]);
        else
          ((float*)Cv)[(size_t)(r0 + r) * N + c0] = acc[mi][ni][r];
      }
    }
}

// ---------------- dt = softplus(raw + dt_bias) ----------------
__global__ void k_dt(const unsigned short* __restrict__ zx, const float* __restrict__ dt_bias,
                     float* __restrict__ dt) {
  int id = blockIdx.x * 256 + threadIdx.x;   // BL*64
  int row = id >> 6, h = id & 63;
  float x = bf2f(zx[(size_t)row * DINP + (2 * D_SSM + 2 * D_STATE) + h]) + dt_bias[h];
  dt[id] = (x > 20.f) ? x : log1pf(expf(x));
}

// ---------------- causal depthwise conv (width 3) + bias + SiLU ----------------
__global__ void k_conv(const unsigned short* __restrict__ zx, const float* __restrict__ cw,
                       const float* __restrict__ cbv, unsigned short* __restrict__ out) {
  int id = blockIdx.x * 256 + threadIdx.x;
  if (id >= BL * CONVDIM) return;
  int c = id % CONVDIM;
  int row = id / CONVDIM;
  int b = row >> 11, l = row & 2047;
  float acc = cbv[c];
#pragma unroll
  for (int k = 0; k < 3; k++) {
    int ls = l + k - 2;
    if (ls >= 0)
      acc += bf2f(zx[(size_t)(b * LSEQ + ls) * DINP + D_SSM + c]) * cw[c * 3 + k];
  }
  out[(size_t)row * CONVDIM + c] = f2bf(acc / (1.f + expf(-acc)));
}

// ---------------- CB[l][s] = C[l] . B[s]  per (b,c) chunk (head-independent) ----------------
__global__ __launch_bounds__(256) void k_cb(const unsigned short* __restrict__ xBC,
                                            float* __restrict__ cbuf) {
  int bc = blockIdx.x;          // b*16 + c
  int row0 = bc * CHUNK;
  int t = threadIdx.x;
  __shared__ float Cs[32 * 132];
  int s = t & 127, lh = t >> 7; // lh in {0,1}
  for (int lt = 0; lt < 4; lt++) {
    __syncthreads();
    for (int i = t; i < 32 * 128; i += 256) {
      int l = i >> 7, n = i & 127;
      Cs[l * 132 + n] = bf2f(xBC[(size_t)(row0 + lt * 32 + l) * CONVDIM + COFF + n]);
    }
    __syncthreads();
    float acc[16];
#pragma unroll
    for (int j = 0; j < 16; j++) acc[j] = 0.f;
    const unsigned short* bp = xBC + (size_t)(row0 + s) * CONVDIM + BOFF;
    for (int n4 = 0; n4 < 128; n4 += 4) {
      ushort4 bu = *(const ushort4*)(bp + n4);
      float b0 = bf2f(bu.x), b1 = bf2f(bu.y), b2 = bf2f(bu.z), b3 = bf2f(bu.w);
#pragma unroll
      for (int li = 0; li < 16; li++) {
        float4 cv = *(const float4*)&Cs[(lh * 16 + li) * 132 + n4];
        acc[li] += b0 * cv.x + b1 * cv.y + b2 * cv.z + b3 * cv.w;
      }
    }
#pragma unroll
    for (int li = 0; li < 16; li++) {
      int gl = lt * 32 + lh * 16 + li;
      cbuf[((size_t)bc * 128 + gl) * 128 + s] = acc[li];
    }
  }
}

// ---------------- per-chunk raw states via MFMA ----------------
__global__ __launch_bounds__(256, 2) void k_states(
    const unsigned short* __restrict__ xBC, const float* __restrict__ dt,
    const float* __restrict__ A_log, float* __restrict__ states,
    float* __restrict__ dAsum) {
  constexpr int LP = 136;
  int id = blockIdx.x; int h = id & 63; int bc = id >> 6; int row0 = bc * CHUNK;
  int t = threadIdx.x;
  __shared__ float Acum[128];
  __shared__ float wdec[128];
  __shared__ __align__(16) unsigned short Bt[128 * LP]; // [n][l^]
  __shared__ __align__(16) unsigned short Xt[64 * LP];  // [p][l^]
  float Ah = -expf(A_log[h]);
  if (t < 128) Acum[t] = dt[(size_t)(row0 + t) * 64 + h] * Ah;
  __syncthreads();
  for (int off = 1; off < 128; off <<= 1) {
    float v = 0.f;
    bool act = (t < 128) && (t >= off);
    if (act) v = Acum[t - off];
    __syncthreads();
    if (act) Acum[t] += v;
    __syncthreads();
  }
  float Alast = Acum[127];
  if (t < 128) wdec[t] = expf(Alast - Acum[t]);
  if (t == 0) dAsum[id] = Alast;
  __syncthreads();
  for (int i = t; i < 16 * 128; i += 256) {
    int l = i >> 4, n0 = (i & 15) * 8;
    const unsigned short* src = xBC + (size_t)(row0 + l) * CONVDIM + BOFF + n0;
    ushort4 v0 = *(const ushort4*)src;
    ushort4 v1 = *(const ushort4*)(src + 4);
    float wl = wdec[l];
    int ls = l ^ (n0 & 24);
    Bt[(n0 + 0) * LP + ls] = f2bf(bf2f(v0.x) * wl);
    Bt[(n0 + 1) * LP + ls] = f2bf(bf2f(v0.y) * wl);
    Bt[(n0 + 2) * LP + ls] = f2bf(bf2f(v0.z) * wl);
    Bt[(n0 + 3) * LP + ls] = f2bf(bf2f(v0.w) * wl);
    Bt[(n0 + 4) * LP + ls] = f2bf(bf2f(v1.x) * wl);
    Bt[(n0 + 5) * LP + ls] = f2bf(bf2f(v1.y) * wl);
    Bt[(n0 + 6) * LP + ls] = f2bf(bf2f(v1.z) * wl);
    Bt[(n0 + 7) * LP + ls] = f2bf(bf2f(v1.w) * wl);
  }
  for (int i = t; i < 8 * 128; i += 256) {
    int l = i >> 3, p0 = (i & 7) * 8;
    const unsigned short* src = xBC + (size_t)(row0 + l) * CONVDIM + h * HEADDIM + p0;
    ushort4 v0 = *(const ushort4*)src;
    ushort4 v1 = *(const ushort4*)(src + 4);
    float dl = dt[(size_t)(row0 + l) * 64 + h];
    int ls = l ^ (p0 & 24);
    Xt[(p0 + 0) * LP + ls] = f2bf(bf2f(v0.x) * dl);
    Xt[(p0 + 1) * LP + ls] = f2bf(bf2f(v0.y) * dl);
    Xt[(p0 + 2) * LP + ls] = f2bf(bf2f(v0.z) * dl);
    Xt[(p0 + 3) * LP + ls] = f2bf(bf2f(v0.w) * dl);
    Xt[(p0 + 4) * LP + ls] = f2bf(bf2f(v1.x) * dl);
    Xt[(p0 + 5) * LP + ls] = f2bf(bf2f(v1.y) * dl);
    Xt[(p0 + 6) * LP + ls] = f2bf(bf2f(v1.z) * dl);
    Xt[(p0 + 7) * LP + ls] = f2bf(bf2f(v1.w) * dl);
  }
  __syncthreads();
  int w = t >> 6, lane = t & 63;
  int lr = lane & 15, lk = (lane >> 4) * 8;
  int pp = w * 16 + lr;
  f32x4 acc[8] = {};
  for (int k0 = 0; k0 < 128; k0 += 32) {
    bf16x8 af = *(const bf16x8*)&Xt[pp * LP + ((k0 + lk) ^ (pp & 24))];
#pragma unroll
    for (int nt = 0; nt < 8; nt++) {
      int nn = nt * 16 + lr;
      bf16x8 bfr = *(const bf16x8*)&Bt[nn * LP + ((k0 + lk) ^ (nn & 24))];
      acc[nt] = __builtin_amdgcn_mfma_f32_16x16x32_bf16(af, bfr, acc[nt], 0, 0, 0);
    }
  }
  float* sp = states + (size_t)id * 8192;
  int orow = (lane >> 4) * 4, ocol = lane & 15;
#pragma unroll
  for (int nt = 0; nt < 8; nt++)
#pragma unroll
    for (int r = 0; r < 4; r++)
      sp[(w * 16 + orow + r) * 128 + nt * 16 + ocol] = acc[nt][r];
}

// ---------------- inter-chunk recurrence, 16-way split of state vector ----------------
__global__ __launch_bounds__(256) void k_scan(float* __restrict__ states,
                                              const float* __restrict__ dAsum) {
  int blk = blockIdx.x;              // (b*64+h)*16 + seg
  int seg = blk & 15, bh = blk >> 4;
  int b = bh >> 6, h = bh & 63;
  int e = seg * 512 + threadIdx.x * 2;
  float cx = 0.f, cy = 0.f;
  for (int c = 0; c < NCH; c++) {
    int bc = b * NCH + c;
    float* p = states + ((size_t)bc * 64 + h) * 8192 + e;
    float dec = expf(dAsum[bc * 64 + h]);
    float2 raw = *(float2*)p;
    float2 cur = {cx, cy};
    *(float2*)p = cur;
    cx = cx * dec + raw.x;
    cy = cy * dec + raw.y;
  }
}

// ---------------- Y = Y_off + Y_diag + D*x via MFMA; Y in place over states ----------------
// Phase A: Y_off[l][p] = sum_n (C[l,n]*e^Acum[l]) * S[p,n]      (A=[l][n], B=[p][n])
// Phase B: Y_diag[l][p] = sum_s M[l,s] * (x[s,p]*dt[s])         (A=[l][s], B=Xt[p][s])
__global__ __launch_bounds__(256, 2) void k_ssd_y(
    const unsigned short* __restrict__ xBC, const float* __restrict__ dt,
    float* __restrict__ states, const float* __restrict__ cbuf,
    const float* __restrict__ A_log, const float* __restrict__ Dv) {
  constexpr int LP = 136;
  int id = blockIdx.x;
  int h = id & 63, bc = id >> 6;
  int row0 = bc * CHUNK;
  int t = threadIdx.x;
  __shared__ float Acum[128];
  __shared__ __align__(16) unsigned short LA[64 * LP];   // S (phase A), Xt (phase B)
  __shared__ __align__(16) unsigned short LB[128 * LP];  // Cexp (phase A), M (phase B)
  float Ah = -expf(A_log[h]);
  if (t < 128) Acum[t] = dt[(size_t)(row0 + t) * 64 + h] * Ah;
  __syncthreads();
  for (int off = 1; off < 128; off <<= 1) {
    float v = 0.f;
    bool act = (t < 128) && (t >= off);
    if (act) v = Acum[t - off];
    __syncthreads();
    if (act) Acum[t] += v;
    __syncthreads();
  }
  float* sp = states + (size_t)id * 8192;
  // ---- Phase A staging: S (fp32 global -> bf16 LDS, [p][n]) and Cexp ([l][n]) ----
  for (int i4 = t; i4 < 2048; i4 += 256) {
    int p = i4 >> 5, n0 = (i4 & 31) * 4;
    float4 v = *(const float4*)(sp + p * 128 + n0);
    ushort4 o; o.x = f2bf(v.x); o.y = f2bf(v.y); o.z = f2bf(v.z); o.w = f2bf(v.w);
    *(ushort4*)&LA[p * LP + n0] = o;
  }
  for (int i = t; i < 16 * 128; i += 256) {
    int l = i >> 4, n0 = (i & 15) * 8;
    const unsigned short* src = xBC + (size_t)(row0 + l) * CONVDIM + COFF + n0;
    ushort4 v0 = *(const ushort4*)src;
    ushort4 v1 = *(const ushort4*)(src + 4);
    float el = expf(Acum[l]);
    ushort4 o0, o1;
    o0.x = f2bf(bf2f(v0.x) * el); o0.y = f2bf(bf2f(v0.y) * el);
    o0.z = f2bf(bf2f(v0.z) * el); o0.w = f2bf(bf2f(v0.w) * el);
    o1.x = f2bf(bf2f(v1.x) * el); o1.y = f2bf(bf2f(v1.y) * el);
    o1.z = f2bf(bf2f(v1.z) * el); o1.w = f2bf(bf2f(v1.w) * el);
    *(ushort4*)&LB[l * LP + n0] = o0;
    *(ushort4*)&LB[l * LP + n0 + 4] = o1;
  }
  __syncthreads();
  int w = t >> 6, lane = t & 63;
  int lr = lane & 15, lk = (lane >> 4) * 8;
  f32x4 acc[2][4] = {};
  // ---- Phase A MFMA: rows l in [w*32, w*32+32) ----
#pragma unroll
  for (int k0 = 0; k0 < 128; k0 += 32) {
    bf16x8 af[2], bfv[4];
#pragma unroll
    for (int mt = 0; mt < 2; mt++)
      af[mt] = *(const bf16x8*)&LB[(w * 32 + mt * 16 + lr) * LP + k0 + lk];
#pragma unroll
    for (int nt = 0; nt < 4; nt++)
      bfv[nt] = *(const bf16x8*)&LA[(nt * 16 + lr) * LP + k0 + lk];
#pragma unroll
    for (int mt = 0; mt < 2; mt++)
#pragma unroll
      for (int nt = 0; nt < 4; nt++)
        acc[mt][nt] = __builtin_amdgcn_mfma_f32_16x16x32_bf16(af[mt], bfv[nt], acc[mt][nt], 0, 0, 0);
  }
  __syncthreads();
  // ---- Phase B staging: M = CB .* decay mask ([l][s]) and Xt = (x*dt)^T ([p][s^]) ----
  for (int i = t; i < 16 * 128; i += 256) {
    int l = i >> 4, s0 = (i & 15) * 8;
    const float* cbp = cbuf + ((size_t)bc * 128 + l) * 128 + s0;
    float4 c0 = *(const float4*)cbp;
    float4 c1 = *(const float4*)(cbp + 4);
    float al = Acum[l];
    ushort4 o0, o1;
    o0.x = (s0 + 0 <= l) ? f2bf(c0.x * expf(al - Acum[s0 + 0])) : 0;
    o0.y = (s0 + 1 <= l) ? f2bf(c0.y * expf(al - Acum[s0 + 1])) : 0;
    o0.z = (s0 + 2 <= l) ? f2bf(c0.z * expf(al - Acum[s0 + 2])) : 0;
    o0.w = (s0 + 3 <= l) ? f2bf(c0.w * expf(al - Acum[s0 + 3])) : 0;
    o1.x = (s0 + 4 <= l) ? f2bf(c1.x * expf(al - Acum[s0 + 4])) : 0;
    o1.y = (s0 + 5 <= l) ? f2bf(c1.y * expf(al - Acum[s0 + 5])) : 0;
    o1.z = (s0 + 6 <= l) ? f2bf(c1.z * expf(al - Acum[s0 + 6])) : 0;
    o1.w = (s0 + 7 <= l) ? f2bf(c1.w * expf(al - Acum[s0 + 7])) : 0;
    *(ushort4*)&LB[l * LP + s0] = o0;
    *(ushort4*)&LB[l * LP + s0 + 4] = o1;
  }
  for (int i = t; i < 8 * 128; i += 256) {
    int s = i >> 3, p0 = (i & 7) * 8;
    const unsigned short* src = xBC + (size_t)(row0 + s) * CONVDIM + h * HEADDIM + p0;
    ushort4 v0 = *(const ushort4*)src;
    ushort4 v1 = *(const ushort4*)(src + 4);
    float dl = dt[(size_t)(row0 + s) * 64 + h];
    int ss = s ^ (p0 & 24);
    LA[(p0 + 0) * LP + ss] = f2bf(bf2f(v0.x) * dl);
    LA[(p0 + 1) * LP + ss] = f2bf(bf2f(v0.y) * dl);
    LA[(p0 + 2) * LP + ss] = f2bf(bf2f(v0.z) * dl);
    LA[(p0 + 3) * LP + ss] = f2bf(bf2f(v0.w) * dl);
    LA[(p0 + 4) * LP + ss] = f2bf(bf2f(v1.x) * dl);
    LA[(p0 + 5) * LP + ss] = f2bf(bf2f(v1.y) * dl);
    LA[(p0 + 6) * LP + ss] = f2bf(bf2f(v1.z) * dl);
    LA[(p0 + 7) * LP + ss] = f2bf(bf2f(v1.w) * dl);
  }
  __syncthreads();
  // ---- Phase B MFMA ----
#pragma unroll
  for (int k0 = 0; k0 < 128; k0 += 32) {
    bf16x8 af[2], bfv[4];
#pragma unroll
    for (int mt = 0; mt < 2; mt++)
      af[mt] = *(const bf16x8*)&LB[(w * 32 + mt * 16 + lr) * LP + k0 + lk];
#pragma unroll
    for (int nt = 0; nt < 4; nt++) {
      int pp = nt * 16 + lr;
      bfv[nt] = *(const bf16x8*)&LA[pp * LP + ((k0 + lk) ^ (pp & 24))];
    }
#pragma unroll
    for (int mt = 0; mt < 2; mt++)
#pragma unroll
      for (int nt = 0; nt < 4; nt++)
        acc[mt][nt] = __builtin_amdgcn_mfma_f32_16x16x32_bf16(af[mt], bfv[nt], acc[mt][nt], 0, 0, 0);
  }
  // ---- epilogue: Y = acc + D*x, in place over states, layout [l][p] ----
  float Dh = Dv[h];
  int orow = (lane >> 4) * 4, ocol = lane & 15;
#pragma unroll
  for (int mt = 0; mt < 2; mt++)
#pragma unroll
    for (int nt = 0; nt < 4; nt++) {
      int l0 = w * 32 + mt * 16 + orow;
      int p = nt * 16 + ocol;
#pragma unroll
      for (int r = 0; r < 4; r++) {
        int l = l0 + r;
        float xv = bf2f(xBC[(size_t)(row0 + l) * CONVDIM + h * HEADDIM + p]);
        sp[l * 64 + p] = acc[mt][nt][r] + Dh * xv;
      }
    }
}

// ---------------- gate (silu(z)), RMS norm, scale, -> bf16 ----------------
__global__ __launch_bounds__(256) void k_gate_rms(
    const float* __restrict__ Yst, const unsigned short* __restrict__ zx,
    const float* __restrict__ norm_w, unsigned short* __restrict__ ybf) {
  int row = blockIdx.x, t = threadIdx.x;
  int bc = row >> 7, ll = row & 127;
  float vals[16];
  float ss = 0.f;
#pragma unroll
  for (int j = 0; j < 16; j++) {
    int d = t + j * 256;
    int h = d >> 6, p = d & 63;
    float yv = Yst[(((size_t)bc * 64 + h) * 8192) + ll * 64 + p];
    float z = bf2f(zx[(size_t)row * DINP + d]);
    float g = yv * (z / (1.f + expf(-z)));
    vals[j] = g;
    ss += g * g;
  }
#pragma unroll
  for (int off = 32; off > 0; off >>= 1) ss += __shfl_down(ss, off, 64);
  __shared__ float red[4];
  if ((t & 63) == 0) red[t >> 6] = ss;
  __syncthreads();
  float tot = red[0] + red[1] + red[2] + red[3];
  float rms = rsqrtf(tot / (float)D_SSM + 1e-5f);
#pragma unroll
  for (int j = 0; j < 16; j++) {
    int d = t + j * 256;
    ybf[(size_t)row * D_SSM + d] = f2bf(vals[j] * rms * norm_w[d]);
  }
}

// ---------------- out += out[:, ::-1, :] (in place, pairwise) ----------------
__global__ void k_flipadd(float* __restrict__ out) {
  int id = blockIdx.x * 256 + threadIdx.x;   // B * (L/2) * D_MODEL
  int d = id & 2047;
  int rem = id >> 11;
  int l = rem & 1023;
  int b = rem >> 10;
  size_t i1 = ((size_t)b * LSEQ + l) * D_MODEL + d;
  size_t i2 = ((size_t)b * LSEQ + (LSEQ - 1 - l)) * D_MODEL + d;
  float a = out[i1], c = out[i2];
  out[i1] = a + c;
  out[i2] = a + c;
}

// ---------------- launch ----------------
extern "C" void kernel_launch(void* const* d_in, const int* in_sizes, int n_in,
                              void* d_out, int out_size, void* d_ws, size_t ws_size,
                              hipStream_t stream) {
  if (ws_size < WS_NEED) return;   // fail cleanly instead of OOB-faulting
  const float* u       = (const float*)d_in[0];
  const float* W_in    = (const float*)d_in[1];
  const float* conv_w  = (const float*)d_in[2];
  const float* conv_b  = (const float*)d_in[3];
  const float* dt_bias = (const float*)d_in[4];
  const float* A_log   = (const float*)d_in[5];
  const float* Dv      = (const float*)d_in[6];
  const float* norm_w  = (const float*)d_in[7];
  const float* W_out   = (const float*)d_in[8];
  float* out = (float*)d_out;
  char* ws = (char*)d_ws;

  unsigned short* winb = (unsigned short*)(ws + OFF_WIN); // later: y bf16
  unsigned short* ub   = (unsigned short*)(ws + OFF_UB);  // later: W_out bf16
  unsigned short* zx   = (unsigned short*)(ws + OFF_ZX);
  unsigned short* xbc  = (unsigned short*)(ws + OFF_XBC);
  float* dtb  = (float*)(ws + OFF_DT);
  float* st   = (float*)(ws + OFF_ST);   // states, then Y in place
  float* cbuf = (float*)(ws + OFF_CB);
  float* dAs  = (float*)(ws + OFF_DAS);

  k_cvt4<<<2097152 / 256, 256, 0, stream>>>((const float4*)u, (ushort4*)ub, 2097152, 2097152);
  k_cvt4<<<4390912 / 256, 256, 0, stream>>>((const float4*)W_in, (ushort4*)winb, 4390912, 4358144);
  k_gemm_bt<true><<<dim3(DINP / 128, BL / 128), 256, 0, stream>>>(ub, winb, zx, BL, DINP, D_MODEL);
  k_cvt4<<<2097152 / 256, 256, 0, stream>>>((const float4*)W_out, (ushort4*)ub, 2097152, 2097152);
  k_dt<<<BL * 64 / 256, 256, 0, stream>>>(zx, dt_bias, dtb);
  k_conv<<<(BL * CONVDIM) / 256, 256, 0, stream>>>(zx, conv_w, conv_b, xbc);
  k_cb<<<B_SZ * NCH, 256, 0, stream>>>(xbc, cbuf);
  k_states<<<B_SZ * NCH * NHEADS, 256, 0, stream>>>(xbc, dtb, A_log, st, dAs);
  k_scan<<<B_SZ * NHEADS * 16, 256, 0, stream>>>(st, dAs);
  k_ssd_y<<<B_SZ * NCH * NHEADS, 256, 0, stream>>>(xbc, dtb, st, cbuf, A_log, Dv);
  k_gate_rms<<<BL, 256, 0, stream>>>(st, zx, norm_w, winb);
  k_gemm_bt<false><<<dim3(D_MODEL / 128, BL / 128), 256, 0, stream>>>(winb, ub, out, BL, D_MODEL, D_SSM);
  k_flipadd<<<(B_SZ * (LSEQ / 2) * D_MODEL) / 256, 256, 0, stream>>>(out);
}

// Round 5
// 695.228 us; speedup vs baseline: 8.3311x; 1.0471x over previous
//
#include <hip/hip_runtime.h>

// ---------------- problem constants ----------------
constexpr int B_SZ = 2, LSEQ = 2048, D_MODEL = 2048;
constexpr int D_SSM = 4096, D_STATE = 128, NHEADS = 64, HEADDIM = 64;
constexpr int CHUNK = 128;
constexpr int NCH = LSEQ / CHUNK;             // 16
constexpr int BL = B_SZ * LSEQ;               // 4096 token rows
constexpr int DIN = 2 * D_SSM + 2 * D_STATE + NHEADS; // 8512
constexpr int DINP = 8576;                    // padded to 67*128
constexpr int CONVDIM = D_SSM + 2 * D_STATE;  // 4352
constexpr int BOFF = D_SSM;                   // B offset inside xBC_conv
constexpr int COFF = D_SSM + D_STATE;         // C offset inside xBC_conv

// ---------------- workspace layout (bytes) — total ~218 MiB ----------------
constexpr size_t OFF_WIN = 0;                                      // W_in bf16 -> later y bf16
constexpr size_t OFF_UB  = OFF_WIN + (size_t)DINP * D_MODEL * 2;   // u bf16 -> later W_out bf16
constexpr size_t OFF_ZX  = OFF_UB + (size_t)BL * D_MODEL * 2;      // zxbcdt bf16 (BL x DINP)
constexpr size_t OFF_XBC = OFF_ZX + (size_t)BL * DINP * 2;         // conv output bf16 (BL x 4352)
constexpr size_t OFF_DT  = OFF_XBC + (size_t)BL * CONVDIM * 2;     // dt fp32 (BL x 64)
constexpr size_t OFF_ST  = OFF_DT + (size_t)BL * NHEADS * 4;       // states fp32 (2048 x 8192), reused as Y
constexpr size_t OFF_CB  = OFF_ST + (size_t)B_SZ * NCH * NHEADS * HEADDIM * D_STATE * 4;
constexpr size_t OFF_DAS = OFF_CB + (size_t)B_SZ * NCH * CHUNK * CHUNK * 4;
constexpr size_t WS_NEED = OFF_DAS + (size_t)B_SZ * NCH * NHEADS * 4 + 4096;

typedef float f32x4 __attribute__((ext_vector_type(4)));
typedef __bf16 bf16x8 __attribute__((ext_vector_type(8)));

__device__ __forceinline__ unsigned short f2bf(float f) {
  unsigned int x = __float_as_uint(f);
  x += 0x7fffu + ((x >> 16) & 1u);   // round-to-nearest-even
  return (unsigned short)(x >> 16);
}
__device__ __forceinline__ float bf2f(unsigned short u) {
  return __uint_as_float(((unsigned int)u) << 16);
}

// async global->LDS, 16 B per lane; LDS dest = wave-uniform base + lane*16
__device__ __forceinline__ void llds16(const unsigned short* g, unsigned short* l) {
  __builtin_amdgcn_global_load_lds(
      (const __attribute__((address_space(1))) unsigned int*)g,
      (__attribute__((address_space(3))) unsigned int*)l, 16, 0, 0);
}

// ---------------- fp32 -> bf16 convert (with zero padding past nsrc4) ----------------
__global__ void k_cvt4(const float4* __restrict__ src, ushort4* __restrict__ dst,
                       int n4, int nsrc4) {
  int i = blockIdx.x * 256 + threadIdx.x;
  if (i >= n4) return;
  float4 v = make_float4(0.f, 0.f, 0.f, 0.f);
  if (i < nsrc4) v = src[i];
  ushort4 o;
  o.x = f2bf(v.x); o.y = f2bf(v.y); o.z = f2bf(v.z); o.w = f2bf(v.w);
  dst[i] = o;
}

// ---------------- bf16 MFMA GEMM: C[M][N] = A[M][K] * B[N][K]^T ----------------
// 128x128 tile, 4 waves, BK=32, async global_load_lds staging.
// LDS k-chunk XOR swizzle kills the 8-way ds_read_b128 bank conflict;
// panel-swizzled 1D grid (8 N-tiles per panel, M innermost) for L2 reuse.
template <bool OUT_BF16>
__global__ __launch_bounds__(256, 2) void k_gemm_bt(
    const unsigned short* __restrict__ A, const unsigned short* __restrict__ Bm,
    void* __restrict__ Cv, int M, int N, int K) {
  __shared__ __align__(16) unsigned short As[128 * 32];
  __shared__ __align__(16) unsigned short Bs[128 * 32];
  int t = threadIdx.x;
  int mt = M >> 7, ntl = N >> 7;
  int bid = blockIdx.x;
  int panel = bid / (8 * mt);
  int within = bid - panel * 8 * mt;
  int pw = min(8, ntl - panel * 8);
  int m0 = (within / pw) * 128;
  int n0 = (panel * 8 + within % pw) * 128;
  int w = t >> 6, lane = t & 63;
  int wm = (w >> 1) * 64, wn = (w & 1) * 64;
  int lr = lane & 15;
  f32x4 acc[4][4] = {};
  // staging: thread t -> row r=t>>2 (and r+64), LDS slot s=t&3 at elem 8t.
  // slot s holds global k-chunk c = s ^ swz(r), swz(r)=(r&3)^((r>>2)&3).
  int sr = t >> 2;
  int swzS = ((sr & 3) ^ ((sr >> 2) & 3));
  int cSrc = ((t & 3) ^ swzS) * 8;
  const unsigned short* Ap = A + (size_t)(m0 + sr) * K + cSrc;
  const unsigned short* Bp = Bm + (size_t)(n0 + sr) * K + cSrc;
  unsigned short* AsW0 = As + w * 512;
  unsigned short* AsW1 = As + 2048 + w * 512;
  unsigned short* BsW0 = Bs + w * 512;
  unsigned short* BsW1 = Bs + 2048 + w * 512;
  // fragment read slot offsets (precompute per mi): row = base + lr
  int rsel = lane >> 4;   // which k-chunk this lane group wants
  for (int k0 = 0; k0 < K; k0 += 32) {
    __syncthreads();
    llds16(Ap + k0, AsW0);
    llds16(Ap + (size_t)64 * K + k0, AsW1);
    llds16(Bp + k0, BsW0);
    llds16(Bp + (size_t)64 * K + k0, BsW1);
    __syncthreads();
    bf16x8 af[4], bfv[4];
#pragma unroll
    for (int i = 0; i < 4; i++) {
      int row = wm + i * 16 + lr;
      int slot = rsel ^ ((row & 3) ^ ((row >> 2) & 3));
      af[i] = *(const bf16x8*)&As[row * 32 + slot * 8];
    }
#pragma unroll
    for (int i = 0; i < 4; i++) {
      int row = wn + i * 16 + lr;
      int slot = rsel ^ ((row & 3) ^ ((row >> 2) & 3));
      bfv[i] = *(const bf16x8*)&Bs[row * 32 + slot * 8];
    }
#pragma unroll
    for (int mi = 0; mi < 4; mi++)
#pragma unroll
      for (int ni = 0; ni < 4; ni++)
        acc[mi][ni] = __builtin_amdgcn_mfma_f32_16x16x32_bf16(af[mi], bfv[ni], acc[mi][ni], 0, 0, 0);
  }
  int orow = (lane >> 4) * 4, ocol = lane & 15;
#pragma unroll
  for (int mi = 0; mi < 4; mi++)
#pragma unroll
    for (int ni = 0; ni < 4; ni++) {
      int r0 = m0 + wm + mi * 16 + orow;
      int c0 = n0 + wn + ni * 16 + ocol;
#pragma unroll
      for (int r = 0; r < 4; r++) {
        if (OUT_BF16)
          ((unsigned short*)Cv)[(size_t)(r0 + r) * N + c0] = f2bf(acc[mi][ni][r]);
        else
          ((float*)Cv)[(size_t)(r0 + r) * N + c0] = acc[mi][ni][r];
      }
    }
}

// ---------------- dt = softplus(raw + dt_bias) ----------------
__global__ void k_dt(const unsigned short* __restrict__ zx, const float* __restrict__ dt_bias,
                     float* __restrict__ dt) {
  int id = blockIdx.x * 256 + threadIdx.x;   // BL*64
  int row = id >> 6, h = id & 63;
  float x = bf2f(zx[(size_t)row * DINP + (2 * D_SSM + 2 * D_STATE) + h]) + dt_bias[h];
  dt[id] = (x > 20.f) ? x : log1pf(expf(x));
}

// ---------------- causal depthwise conv (width 3) + bias + SiLU ----------------
__global__ void k_conv(const unsigned short* __restrict__ zx, const float* __restrict__ cw,
                       const float* __restrict__ cbv, unsigned short* __restrict__ out) {
  int id = blockIdx.x * 256 + threadIdx.x;
  if (id >= BL * CONVDIM) return;
  int c = id % CONVDIM;
  int row = id / CONVDIM;
  int b = row >> 11, l = row & 2047;
  float acc = cbv[c];
#pragma unroll
  for (int k = 0; k < 3; k++) {
    int ls = l + k - 2;
    if (ls >= 0)
      acc += bf2f(zx[(size_t)(b * LSEQ + ls) * DINP + D_SSM + c]) * cw[c * 3 + k];
  }
  out[(size_t)row * CONVDIM + c] = f2bf(acc / (1.f + expf(-acc)));
}

// ---------------- CB[l][s] = C[l] . B[s]  per (b,c) chunk (head-independent) ----------------
__global__ __launch_bounds__(256) void k_cb(const unsigned short* __restrict__ xBC,
                                            float* __restrict__ cbuf) {
  int bc = blockIdx.x;          // b*16 + c
  int row0 = bc * CHUNK;
  int t = threadIdx.x;
  __shared__ float Cs[32 * 132];
  int s = t & 127, lh = t >> 7; // lh in {0,1}
  for (int lt = 0; lt < 4; lt++) {
    __syncthreads();
    for (int i = t; i < 32 * 128; i += 256) {
      int l = i >> 7, n = i & 127;
      Cs[l * 132 + n] = bf2f(xBC[(size_t)(row0 + lt * 32 + l) * CONVDIM + COFF + n]);
    }
    __syncthreads();
    float acc[16];
#pragma unroll
    for (int j = 0; j < 16; j++) acc[j] = 0.f;
    const unsigned short* bp = xBC + (size_t)(row0 + s) * CONVDIM + BOFF;
    for (int n4 = 0; n4 < 128; n4 += 4) {
      ushort4 bu = *(const ushort4*)(bp + n4);
      float b0 = bf2f(bu.x), b1 = bf2f(bu.y), b2 = bf2f(bu.z), b3 = bf2f(bu.w);
#pragma unroll
      for (int li = 0; li < 16; li++) {
        float4 cv = *(const float4*)&Cs[(lh * 16 + li) * 132 + n4];
        acc[li] += b0 * cv.x + b1 * cv.y + b2 * cv.z + b3 * cv.w;
      }
    }
#pragma unroll
    for (int li = 0; li < 16; li++) {
      int gl = lt * 32 + lh * 16 + li;
      cbuf[((size_t)bc * 128 + gl) * 128 + s] = acc[li];
    }
  }
}

// ---------------- per-chunk raw states via MFMA ----------------
__global__ __launch_bounds__(256, 2) void k_states(
    const unsigned short* __restrict__ xBC, const float* __restrict__ dt,
    const float* __restrict__ A_log, float* __restrict__ states,
    float* __restrict__ dAsum) {
  constexpr int LP = 136;
  int id = blockIdx.x; int h = id & 63; int bc = id >> 6; int row0 = bc * CHUNK;
  int t = threadIdx.x;
  __shared__ float Acum[128];
  __shared__ float wdec[128];
  __shared__ __align__(16) unsigned short Bt[128 * LP]; // [n][l^]
  __shared__ __align__(16) unsigned short Xt[64 * LP];  // [p][l^]
  float Ah = -expf(A_log[h]);
  if (t < 128) Acum[t] = dt[(size_t)(row0 + t) * 64 + h] * Ah;
  __syncthreads();
  for (int off = 1; off < 128; off <<= 1) {
    float v = 0.f;
    bool act = (t < 128) && (t >= off);
    if (act) v = Acum[t - off];
    __syncthreads();
    if (act) Acum[t] += v;
    __syncthreads();
  }
  float Alast = Acum[127];
  if (t < 128) wdec[t] = expf(Alast - Acum[t]);
  if (t == 0) dAsum[id] = Alast;
  __syncthreads();
  for (int i = t; i < 16 * 128; i += 256) {
    int l = i >> 4, n0 = (i & 15) * 8;
    const unsigned short* src = xBC + (size_t)(row0 + l) * CONVDIM + BOFF + n0;
    ushort4 v0 = *(const ushort4*)src;
    ushort4 v1 = *(const ushort4*)(src + 4);
    float wl = wdec[l];
    int ls = l ^ (n0 & 24);
    Bt[(n0 + 0) * LP + ls] = f2bf(bf2f(v0.x) * wl);
    Bt[(n0 + 1) * LP + ls] = f2bf(bf2f(v0.y) * wl);
    Bt[(n0 + 2) * LP + ls] = f2bf(bf2f(v0.z) * wl);
    Bt[(n0 + 3) * LP + ls] = f2bf(bf2f(v0.w) * wl);
    Bt[(n0 + 4) * LP + ls] = f2bf(bf2f(v1.x) * wl);
    Bt[(n0 + 5) * LP + ls] = f2bf(bf2f(v1.y) * wl);
    Bt[(n0 + 6) * LP + ls] = f2bf(bf2f(v1.z) * wl);
    Bt[(n0 + 7) * LP + ls] = f2bf(bf2f(v1.w) * wl);
  }
  for (int i = t; i < 8 * 128; i += 256) {
    int l = i >> 3, p0 = (i & 7) * 8;
    const unsigned short* src = xBC + (size_t)(row0 + l) * CONVDIM + h * HEADDIM + p0;
    ushort4 v0 = *(const ushort4*)src;
    ushort4 v1 = *(const ushort4*)(src + 4);
    float dl = dt[(size_t)(row0 + l) * 64 + h];
    int ls = l ^ (p0 & 24);
    Xt[(p0 + 0) * LP + ls] = f2bf(bf2f(v0.x) * dl);
    Xt[(p0 + 1) * LP + ls] = f2bf(bf2f(v0.y) * dl);
    Xt[(p0 + 2) * LP + ls] = f2bf(bf2f(v0.z) * dl);
    Xt[(p0 + 3) * LP + ls] = f2bf(bf2f(v0.w) * dl);
    Xt[(p0 + 4) * LP + ls] = f2bf(bf2f(v1.x) * dl);
    Xt[(p0 + 5) * LP + ls] = f2bf(bf2f(v1.y) * dl);
    Xt[(p0 + 6) * LP + ls] = f2bf(bf2f(v1.z) * dl);
    Xt[(p0 + 7) * LP + ls] = f2bf(bf2f(v1.w) * dl);
  }
  __syncthreads();
  int w = t >> 6, lane = t & 63;
  int lr = lane & 15, lk = (lane >> 4) * 8;
  int pp = w * 16 + lr;
  f32x4 acc[8] = {};
  for (int k0 = 0; k0 < 128; k0 += 32) {
    bf16x8 af = *(const bf16x8*)&Xt[pp * LP + ((k0 + lk) ^ (pp & 24))];
#pragma unroll
    for (int nt = 0; nt < 8; nt++) {
      int nn = nt * 16 + lr;
      bf16x8 bfr = *(const bf16x8*)&Bt[nn * LP + ((k0 + lk) ^ (nn & 24))];
      acc[nt] = __builtin_amdgcn_mfma_f32_16x16x32_bf16(af, bfr, acc[nt], 0, 0, 0);
    }
  }
  float* sp = states + (size_t)id * 8192;
  int orow = (lane >> 4) * 4, ocol = lane & 15;
#pragma unroll
  for (int nt = 0; nt < 8; nt++)
#pragma unroll
    for (int r = 0; r < 4; r++)
      sp[(w * 16 + orow + r) * 128 + nt * 16 + ocol] = acc[nt][r];
}

// ---------------- inter-chunk recurrence, 16-way split of state vector ----------------
__global__ __launch_bounds__(256) void k_scan(float* __restrict__ states,
                                              const float* __restrict__ dAsum) {
  int blk = blockIdx.x;              // (b*64+h)*16 + seg
  int seg = blk & 15, bh = blk >> 4;
  int b = bh >> 6, h = bh & 63;
  int e = seg * 512 + threadIdx.x * 2;
  float cx = 0.f, cy = 0.f;
  for (int c = 0; c < NCH; c++) {
    int bc = b * NCH + c;
    float* p = states + ((size_t)bc * 64 + h) * 8192 + e;
    float dec = expf(dAsum[bc * 64 + h]);
    float2 raw = *(float2*)p;
    float2 cur = {cx, cy};
    *(float2*)p = cur;
    cx = cx * dec + raw.x;
    cy = cy * dec + raw.y;
  }
}

// ---------------- Y = Y_off + Y_diag + D*x via MFMA; Y in place over states ----------------
__global__ __launch_bounds__(256, 2) void k_ssd_y(
    const unsigned short* __restrict__ xBC, const float* __restrict__ dt,
    float* __restrict__ states, const float* __restrict__ cbuf,
    const float* __restrict__ A_log, const float* __restrict__ Dv) {
  constexpr int LP = 136;
  int id = blockIdx.x;
  int h = id & 63, bc = id >> 6;
  int row0 = bc * CHUNK;
  int t = threadIdx.x;
  __shared__ float Acum[128];
  __shared__ __align__(16) unsigned short LA[64 * LP];   // S (phase A), Xt (phase B)
  __shared__ __align__(16) unsigned short LB[128 * LP];  // Cexp (phase A), M (phase B)
  float Ah = -expf(A_log[h]);
  if (t < 128) Acum[t] = dt[(size_t)(row0 + t) * 64 + h] * Ah;
  __syncthreads();
  for (int off = 1; off < 128; off <<= 1) {
    float v = 0.f;
    bool act = (t < 128) && (t >= off);
    if (act) v = Acum[t - off];
    __syncthreads();
    if (act) Acum[t] += v;
    __syncthreads();
  }
  float* sp = states + (size_t)id * 8192;
  for (int i4 = t; i4 < 2048; i4 += 256) {
    int p = i4 >> 5, n0 = (i4 & 31) * 4;
    float4 v = *(const float4*)(sp + p * 128 + n0);
    ushort4 o; o.x = f2bf(v.x); o.y = f2bf(v.y); o.z = f2bf(v.z); o.w = f2bf(v.w);
    *(ushort4*)&LA[p * LP + n0] = o;
  }
  for (int i = t; i < 16 * 128; i += 256) {
    int l = i >> 4, n0 = (i & 15) * 8;
    const unsigned short* src = xBC + (size_t)(row0 + l) * CONVDIM + COFF + n0;
    ushort4 v0 = *(const ushort4*)src;
    ushort4 v1 = *(const ushort4*)(src + 4);
    float el = expf(Acum[l]);
    ushort4 o0, o1;
    o0.x = f2bf(bf2f(v0.x) * el); o0.y = f2bf(bf2f(v0.y) * el);
    o0.z = f2bf(bf2f(v0.z) * el); o0.w = f2bf(bf2f(v0.w) * el);
    o1.x = f2bf(bf2f(v1.x) * el); o1.y = f2bf(bf2f(v1.y) * el);
    o1.z = f2bf(bf2f(v1.z) * el); o1.w = f2bf(bf2f(v1.w) * el);
    *(ushort4*)&LB[l * LP + n0] = o0;
    *(ushort4*)&LB[l * LP + n0 + 4] = o1;
  }
  __syncthreads();
  int w = t >> 6, lane = t & 63;
  int lr = lane & 15, lk = (lane >> 4) * 8;
  f32x4 acc[2][4] = {};
#pragma unroll
  for (int k0 = 0; k0 < 128; k0 += 32) {
    bf16x8 af[2], bfv[4];
#pragma unroll
    for (int mt = 0; mt < 2; mt++)
      af[mt] = *(const bf16x8*)&LB[(w * 32 + mt * 16 + lr) * LP + k0 + lk];
#pragma unroll
    for (int nt = 0; nt < 4; nt++)
      bfv[nt] = *(const bf16x8*)&LA[(nt * 16 + lr) * LP + k0 + lk];
#pragma unroll
    for (int mt = 0; mt < 2; mt++)
#pragma unroll
      for (int nt = 0; nt < 4; nt++)
        acc[mt][nt] = __builtin_amdgcn_mfma_f32_16x16x32_bf16(af[mt], bfv[nt], acc[mt][nt], 0, 0, 0);
  }
  __syncthreads();
  for (int i = t; i < 16 * 128; i += 256) {
    int l = i >> 4, s0 = (i & 15) * 8;
    const float* cbp = cbuf + ((size_t)bc * 128 + l) * 128 + s0;
    float4 c0 = *(const float4*)cbp;
    float4 c1 = *(const float4*)(cbp + 4);
    float al = Acum[l];
    ushort4 o0, o1;
    o0.x = (s0 + 0 <= l) ? f2bf(c0.x * expf(al - Acum[s0 + 0])) : 0;
    o0.y = (s0 + 1 <= l) ? f2bf(c0.y * expf(al - Acum[s0 + 1])) : 0;
    o0.z = (s0 + 2 <= l) ? f2bf(c0.z * expf(al - Acum[s0 + 2])) : 0;
    o0.w = (s0 + 3 <= l) ? f2bf(c0.w * expf(al - Acum[s0 + 3])) : 0;
    o1.x = (s0 + 4 <= l) ? f2bf(c1.x * expf(al - Acum[s0 + 4])) : 0;
    o1.y = (s0 + 5 <= l) ? f2bf(c1.y * expf(al - Acum[s0 + 5])) : 0;
    o1.z = (s0 + 6 <= l) ? f2bf(c1.z * expf(al - Acum[s0 + 6])) : 0;
    o1.w = (s0 + 7 <= l) ? f2bf(c1.w * expf(al - Acum[s0 + 7])) : 0;
    *(ushort4*)&LB[l * LP + s0] = o0;
    *(ushort4*)&LB[l * LP + s0 + 4] = o1;
  }
  for (int i = t; i < 8 * 128; i += 256) {
    int s = i >> 3, p0 = (i & 7) * 8;
    const unsigned short* src = xBC + (size_t)(row0 + s) * CONVDIM + h * HEADDIM + p0;
    ushort4 v0 = *(const ushort4*)src;
    ushort4 v1 = *(const ushort4*)(src + 4);
    float dl = dt[(size_t)(row0 + s) * 64 + h];
    int ss = s ^ (p0 & 24);
    LA[(p0 + 0) * LP + ss] = f2bf(bf2f(v0.x) * dl);
    LA[(p0 + 1) * LP + ss] = f2bf(bf2f(v0.y) * dl);
    LA[(p0 + 2) * LP + ss] = f2bf(bf2f(v0.z) * dl);
    LA[(p0 + 3) * LP + ss] = f2bf(bf2f(v0.w) * dl);
    LA[(p0 + 4) * LP + ss] = f2bf(bf2f(v1.x) * dl);
    LA[(p0 + 5) * LP + ss] = f2bf(bf2f(v1.y) * dl);
    LA[(p0 + 6) * LP + ss] = f2bf(bf2f(v1.z) * dl);
    LA[(p0 + 7) * LP + ss] = f2bf(bf2f(v1.w) * dl);
  }
  __syncthreads();
#pragma unroll
  for (int k0 = 0; k0 < 128; k0 += 32) {
    bf16x8 af[2], bfv[4];
#pragma unroll
    for (int mt = 0; mt < 2; mt++)
      af[mt] = *(const bf16x8*)&LB[(w * 32 + mt * 16 + lr) * LP + k0 + lk];
#pragma unroll
    for (int nt = 0; nt < 4; nt++) {
      int pp = nt * 16 + lr;
      bfv[nt] = *(const bf16x8*)&LA[pp * LP + ((k0 + lk) ^ (pp & 24))];
    }
#pragma unroll
    for (int mt = 0; mt < 2; mt++)
#pragma unroll
      for (int nt = 0; nt < 4; nt++)
        acc[mt][nt] = __builtin_amdgcn_mfma_f32_16x16x32_bf16(af[mt], bfv[nt], acc[mt][nt], 0, 0, 0);
  }
  float Dh = Dv[h];
  int orow = (lane >> 4) * 4, ocol = lane & 15;
#pragma unroll
  for (int mt = 0; mt < 2; mt++)
#pragma unroll
    for (int nt = 0; nt < 4; nt++) {
      int l0 = w * 32 + mt * 16 + orow;
      int p = nt * 16 + ocol;
#pragma unroll
      for (int r = 0; r < 4; r++) {
        int l = l0 + r;
        float xv = bf2f(xBC[(size_t)(row0 + l) * CONVDIM + h * HEADDIM + p]);
        sp[l * 64 + p] = acc[mt][nt][r] + Dh * xv;
      }
    }
}

// ---------------- gate (silu(z)), RMS norm, scale, -> bf16 ----------------
__global__ __launch_bounds__(256) void k_gate_rms(
    const float* __restrict__ Yst, const unsigned short* __restrict__ zx,
    const float* __restrict__ norm_w, unsigned short* __restrict__ ybf) {
  int row = blockIdx.x, t = threadIdx.x;
  int bc = row >> 7, ll = row & 127;
  float vals[16];
  float ss = 0.f;
#pragma unroll
  for (int j = 0; j < 16; j++) {
    int d = t + j * 256;
    int h = d >> 6, p = d & 63;
    float yv = Yst[(((size_t)bc * 64 + h) * 8192) + ll * 64 + p];
    float z = bf2f(zx[(size_t)row * DINP + d]);
    float g = yv * (z / (1.f + expf(-z)));
    vals[j] = g;
    ss += g * g;
  }
#pragma unroll
  for (int off = 32; off > 0; off >>= 1) ss += __shfl_down(ss, off, 64);
  __shared__ float red[4];
  if ((t & 63) == 0) red[t >> 6] = ss;
  __syncthreads();
  float tot = red[0] + red[1] + red[2] + red[3];
  float rms = rsqrtf(tot / (float)D_SSM + 1e-5f);
#pragma unroll
  for (int j = 0; j < 16; j++) {
    int d = t + j * 256;
    ybf[(size_t)row * D_SSM + d] = f2bf(vals[j] * rms * norm_w[d]);
  }
}

// ---------------- out += out[:, ::-1, :] (in place, pairwise) ----------------
__global__ void k_flipadd(float* __restrict__ out) {
  int id = blockIdx.x * 256 + threadIdx.x;   // B * (L/2) * D_MODEL
  int d = id & 2047;
  int rem = id >> 11;
  int l = rem & 1023;
  int b = rem >> 10;
  size_t i1 = ((size_t)b * LSEQ + l) * D_MODEL + d;
  size_t i2 = ((size_t)b * LSEQ + (LSEQ - 1 - l)) * D_MODEL + d;
  float a = out[i1], c = out[i2];
  out[i1] = a + c;
  out[i2] = a + c;
}

// ---------------- launch ----------------
extern "C" void kernel_launch(void* const* d_in, const int* in_sizes, int n_in,
                              void* d_out, int out_size, void* d_ws, size_t ws_size,
                              hipStream_t stream) {
  if (ws_size < WS_NEED) return;   // fail cleanly instead of OOB-faulting
  const float* u       = (const float*)d_in[0];
  const float* W_in    = (const float*)d_in[1];
  const float* conv_w  = (const float*)d_in[2];
  const float* conv_b  = (const float*)d_in[3];
  const float* dt_bias = (const float*)d_in[4];
  const float* A_log   = (const float*)d_in[5];
  const float* Dv      = (const float*)d_in[6];
  const float* norm_w  = (const float*)d_in[7];
  const float* W_out   = (const float*)d_in[8];
  float* out = (float*)d_out;
  char* ws = (char*)d_ws;

  unsigned short* winb = (unsigned short*)(ws + OFF_WIN); // later: y bf16
  unsigned short* ub   = (unsigned short*)(ws + OFF_UB);  // later: W_out bf16
  unsigned short* zx   = (unsigned short*)(ws + OFF_ZX);
  unsigned short* xbc  = (unsigned short*)(ws + OFF_XBC);
  float* dtb  = (float*)(ws + OFF_DT);
  float* st   = (float*)(ws + OFF_ST);   // states, then Y in place
  float* cbuf = (float*)(ws + OFF_CB);
  float* dAs  = (float*)(ws + OFF_DAS);

  k_cvt4<<<2097152 / 256, 256, 0, stream>>>((const float4*)u, (ushort4*)ub, 2097152, 2097152);
  k_cvt4<<<4390912 / 256, 256, 0, stream>>>((const float4*)W_in, (ushort4*)winb, 4390912, 4358144);
  k_gemm_bt<true><<<(DINP / 128) * (BL / 128), 256, 0, stream>>>(ub, winb, zx, BL, DINP, D_MODEL);
  k_cvt4<<<2097152 / 256, 256, 0, stream>>>((const float4*)W_out, (ushort4*)ub, 2097152, 2097152);
  k_dt<<<BL * 64 / 256, 256, 0, stream>>>(zx, dt_bias, dtb);
  k_conv<<<(BL * CONVDIM) / 256, 256, 0, stream>>>(zx, conv_w, conv_b, xbc);
  k_cb<<<B_SZ * NCH, 256, 0, stream>>>(xbc, cbuf);
  k_states<<<B_SZ * NCH * NHEADS, 256, 0, stream>>>(xbc, dtb, A_log, st, dAs);
  k_scan<<<B_SZ * NHEADS * 16, 256, 0, stream>>>(st, dAs);
  k_ssd_y<<<B_SZ * NCH * NHEADS, 256, 0, stream>>>(xbc, dtb, st, cbuf, A_log, Dv);
  k_gate_rms<<<BL, 256, 0, stream>>>(st, zx, norm_w, winb);
  k_gemm_bt<false><<<(D_MODEL / 128) * (BL / 128), 256, 0, stream>>>(winb, ub, out, BL, D_MODEL, D_SSM);
  k_flipadd<<<(B_SZ * (LSEQ / 2) * D_MODEL) / 256, 256, 0, stream>>>(out);
}